// Round 1
// baseline (8789.881 us; speedup 1.0000x reference)
//
#include <hip/hip_runtime.h>
#include <cmath>

// fusion_36455682409119: EDVR PCD-align style block, fp32.
// Round 0: correctness-first direct convs + mdcn. Later: bf16 MFMA implicit GEMM.
//
// Buffers (d_ws): buf0[B*64*HW], buf1[B*64*HW], corr[B*HW]  (~119 MB)
// d_out doubles as scratch (om region for pack1, off2, feat3) before final write.

constexpr int TS = 16;   // pixel tile
constexpr int CH = 8;    // input-channel chunk

template<int CIN, int OCH, bool TWO_IN, int ACT, bool SCALE, bool RES>
__global__ __launch_bounds__(256)
void conv3x3_kernel(const float* __restrict__ inA, const float* __restrict__ inB,
                    const float* __restrict__ wgt, const float* __restrict__ bias,
                    const float* __restrict__ scale, const float* __restrict__ res,
                    float* __restrict__ out, int H, int W, int COUT)
{
    const int HWp = H * W;
    __shared__ __align__(16) float sIn[CH][18 * 18];
    __shared__ __align__(16) float sW[CH * 9 * OCH];   // layout [c][j][o]

    const int tid = threadIdx.x;
    const int tx = tid & 15, ty = tid >> 4;
    const int nchunk = COUT / OCH;
    const int b   = blockIdx.z / nchunk;
    const int oc0 = (blockIdx.z % nchunk) * OCH;
    const int x = blockIdx.x * TS + tx;
    const int y = blockIdx.y * TS + ty;
    const bool inimg = (x < W) && (y < H);
    const int x0 = blockIdx.x * TS - 1, y0 = blockIdx.y * TS - 1;

    float acc[OCH];
    #pragma unroll
    for (int o = 0; o < OCH; ++o) acc[o] = bias[oc0 + o];

    for (int c0 = 0; c0 < CIN; c0 += CH) {
        __syncthreads();
        // stage input tile (18x18 halo), zero-padded
        for (int idx = tid; idx < CH * 324; idx += 256) {
            int c = idx / 324, r = idx - c * 324;
            int iy = r / 18, ix = r - iy * 18;
            int gy = y0 + iy, gx = x0 + ix;
            float v = 0.f;
            if (gy >= 0 && gy < H && gx >= 0 && gx < W) {
                int cg = c0 + c;
                const float* src;
                if (TWO_IN) {
                    src = (cg < 64) ? (inA + (size_t)(b * 64 + cg) * HWp)
                                    : (inB + (size_t)(b * 64 + cg - 64) * HWp);
                } else {
                    src = inA + (size_t)(b * CIN + cg) * HWp;
                }
                v = src[gy * W + gx];
                if (SCALE) v *= scale[(size_t)b * HWp + gy * W + gx];
            }
            sIn[c][r] = v;
        }
        // stage weights transposed to [c][j][o]
        for (int idx = tid; idx < CH * 9 * OCH; idx += 256) {
            int c = idx / (9 * OCH), r = idx - c * (9 * OCH);
            int j = r / OCH, o = r - j * OCH;
            sW[idx] = wgt[((size_t)(oc0 + o) * CIN + (c0 + c)) * 9 + j];
        }
        __syncthreads();

        #pragma unroll
        for (int c = 0; c < CH; ++c) {
            float v[9];
            #pragma unroll
            for (int ky = 0; ky < 3; ++ky)
                #pragma unroll
                for (int kx = 0; kx < 3; ++kx)
                    v[ky * 3 + kx] = sIn[c][(ty + ky) * 18 + tx + kx];
            #pragma unroll
            for (int j = 0; j < 9; ++j) {
                const float* wrow = &sW[(c * 9 + j) * OCH];
                #pragma unroll
                for (int o = 0; o < OCH; ++o)
                    acc[o] = fmaf(v[j], wrow[o], acc[o]);
            }
        }
    }

    if (inimg) {
        size_t p = (size_t)y * W + x;
        #pragma unroll
        for (int o = 0; o < OCH; ++o) {
            float v = acc[o];
            if (ACT == 1) v = (v >= 0.f) ? v : 0.1f * v;
            if (RES) v += res[((size_t)(b * COUT) + oc0 + o) * HWp + p];
            out[((size_t)(b * COUT) + oc0 + o) * HWp + p] = v;
        }
    }
}

// Modulated deformable conv v2 (3x3, pad 1, dg=8, Cg=8, 64->64), one batch.
// om: [216, HW] = [oy(72) | ox(72) | mask_raw(72)], channel g*9+k within each part.
template<int ACT>
__global__ __launch_bounds__(256)
void mdcn_kernel(const float* __restrict__ x, const float* __restrict__ om,
                 const float* __restrict__ wgt, const float* __restrict__ bias,
                 float* __restrict__ out, int H, int W)
{
    const int HWp = H * W;
    __shared__ __align__(16) float sW[8 * 9 * 64];  // [c][k][o] for current group

    const int tid = threadIdx.x;
    const int tx = tid & 15, ty = tid >> 4;
    const int xo = blockIdx.x * 16 + tx;
    const int yo = blockIdx.y * 16 + ty;
    const bool inimg = (xo < W) && (yo < H);
    const size_t p = (size_t)yo * W + xo;

    float acc[64];
    #pragma unroll
    for (int o = 0; o < 64; ++o) acc[o] = bias[o];

    for (int g = 0; g < 8; ++g) {
        __syncthreads();
        for (int idx = tid; idx < 8 * 9 * 64; idx += 256) {
            int c = idx / (9 * 64), r = idx - c * (9 * 64);
            int j = r / 64, o = r - j * 64;
            sW[idx] = wgt[((size_t)o * 64 + (g * 8 + c)) * 9 + j];
        }
        __syncthreads();

        if (inimg) {
            #pragma unroll
            for (int k = 0; k < 9; ++k) {
                float oy = om[(size_t)(g * 9 + k) * HWp + p];
                float ox = om[(size_t)(72 + g * 9 + k) * HWp + p];
                float mr = om[(size_t)(144 + g * 9 + k) * HWp + p];
                float m = 1.f / (1.f + __expf(-mr));
                float py = (float)yo + (float)(k / 3 - 1) + oy;
                float px = (float)xo + (float)(k % 3 - 1) + ox;
                float y0f = floorf(py), x0f = floorf(px);
                float wy = py - y0f, wx = px - x0f;
                int y0i = (int)y0f, x0i = (int)x0f;
                int y1i = y0i + 1, x1i = x0i + 1;
                bool vy0 = (y0i >= 0) & (y0i < H);
                bool vy1 = (y1i >= 0) & (y1i < H);
                bool vx0 = (x0i >= 0) & (x0i < W);
                bool vx1 = (x1i >= 0) & (x1i < W);
                float w00 = (vy0 & vx0) ? (1.f - wy) * (1.f - wx) : 0.f;
                float w01 = (vy0 & vx1) ? (1.f - wy) * wx         : 0.f;
                float w10 = (vy1 & vx0) ? wy * (1.f - wx)         : 0.f;
                float w11 = (vy1 & vx1) ? wy * wx                 : 0.f;
                int yc0 = min(max(y0i, 0), H - 1), yc1 = min(max(y1i, 0), H - 1);
                int xc0 = min(max(x0i, 0), W - 1), xc1 = min(max(x1i, 0), W - 1);
                size_t i00 = (size_t)yc0 * W + xc0;
                size_t i01 = (size_t)yc0 * W + xc1;
                size_t i10 = (size_t)yc1 * W + xc0;
                size_t i11 = (size_t)yc1 * W + xc1;
                #pragma unroll
                for (int c = 0; c < 8; ++c) {
                    const float* xc = x + (size_t)(g * 8 + c) * HWp;
                    float v = w00 * xc[i00] + w01 * xc[i01] + w10 * xc[i10] + w11 * xc[i11];
                    float sv = v * m;
                    const float* wrow = &sW[(c * 9 + k) * 64];
                    #pragma unroll
                    for (int o = 0; o < 64; ++o)
                        acc[o] = fmaf(sv, wrow[o], acc[o]);
                }
            }
        }
    }

    if (inimg) {
        #pragma unroll
        for (int o = 0; o < 64; ++o) {
            float v = acc[o];
            if (ACT == 1) v = (v >= 0.f) ? v : 0.1f * v;
            out[(size_t)o * HWp + p] = v;
        }
    }
}

__global__ void dot64_kernel(const float* __restrict__ a, const float* __restrict__ b,
                             float* __restrict__ out, int HWp, int B)
{
    int idx = blockIdx.x * blockDim.x + threadIdx.x;
    int total = B * HWp;
    if (idx >= total) return;
    int bb = idx / HWp, pp = idx - bb * HWp;
    const float* pa = a + (size_t)bb * 64 * HWp + pp;
    const float* pb = b + (size_t)bb * 64 * HWp + pp;
    float s = 0.f;
    #pragma unroll
    for (int c = 0; c < 64; ++c)
        s = fmaf(pa[(size_t)c * HWp], pb[(size_t)c * HWp], s);
    out[idx] = s;
}

extern "C" void kernel_launch(void* const* d_in, const int* in_sizes, int n_in,
                              void* d_out, int out_size, void* d_ws, size_t ws_size,
                              hipStream_t stream)
{
    const float* ref    = (const float*)d_in[0];
    const float* neb    = (const float*)d_in[1];
    const float* w_oc1  = (const float*)d_in[2];  const float* b_oc1  = (const float*)d_in[3];
    const float* w_om1  = (const float*)d_in[4];  const float* b_om1  = (const float*)d_in[5];
    const float* w_dcn1 = (const float*)d_in[6];  const float* b_dcn1 = (const float*)d_in[7];
    const float* w_fc   = (const float*)d_in[8];  const float* b_fc   = (const float*)d_in[9];
    const float* w_cas1 = (const float*)d_in[10]; const float* b_cas1 = (const float*)d_in[11];
    const float* w_cas2 = (const float*)d_in[12]; const float* b_cas2 = (const float*)d_in[13];
    const float* w_om2  = (const float*)d_in[14]; const float* b_om2  = (const float*)d_in[15];
    const float* w_dcn2 = (const float*)d_in[16]; const float* b_dcn2 = (const float*)d_in[17];
    const float* w_ta1  = (const float*)d_in[18]; const float* b_ta1  = (const float*)d_in[19];
    const float* w_ta2  = (const float*)d_in[20]; const float* b_ta2  = (const float*)d_in[21];
    const float* w_ff   = (const float*)d_in[22]; const float* b_ff   = (const float*)d_in[23];

    const int B = 4, H = 180, W = 320;
    const size_t HWp = (size_t)H * W;
    const size_t chw = 64 * HWp;

    float* buf0 = (float*)d_ws;          // 4*64*HW
    float* buf1 = buf0 + B * chw;        // 4*64*HW
    float* corr = buf1 + B * chw;        // 4*HW
    float* outp = (float*)d_out;         // doubles as scratch (om1 region / off2 / feat3)

    dim3 blk(256);
    dim3 grd (20, 12, B);   // 320/16, ceil(180/16)
    dim3 grd1(20, 12, 1);
    dim3 grd3(20, 12, 3);   // 216/72 output-channel chunks

    // 1. off1 = lrelu(conv(concat(neb, ref), w_oc1)) -> buf0
    hipLaunchKernelGGL((conv3x3_kernel<128,64,true,1,false,false>), grd, blk, 0, stream,
        neb, ref, w_oc1, b_oc1, nullptr, nullptr, buf0, H, W, 64);

    // 2. pack1 per batch: om = conv(off1[b], w_om1) -> d_out ; feat1[b] = mdcn(neb[b]) -> buf1
    for (int b = 0; b < B; ++b) {
        hipLaunchKernelGGL((conv3x3_kernel<64,72,false,0,false,false>), grd3, blk, 0, stream,
            buf0 + b * chw, nullptr, w_om1, b_om1, nullptr, nullptr, outp, H, W, 216);
        hipLaunchKernelGGL((mdcn_kernel<0>), grd1, blk, 0, stream,
            neb + b * chw, outp, w_dcn1, b_dcn1, buf1 + b * chw, H, W);
    }

    // 3. feat2 = lrelu(conv(feat1, w_fc)) -> buf0   (off1 dead)
    hipLaunchKernelGGL((conv3x3_kernel<64,64,false,1,false,false>), grd, blk, 0, stream,
        buf1, nullptr, w_fc, b_fc, nullptr, nullptr, buf0, H, W, 64);

    // 4. cas_a = lrelu(conv(concat(feat2, ref), w_cas1)) -> buf1  (feat1 dead)
    hipLaunchKernelGGL((conv3x3_kernel<128,64,true,1,false,false>), grd, blk, 0, stream,
        buf0, ref, w_cas1, b_cas1, nullptr, nullptr, buf1, H, W, 64);

    // 5. off2 = lrelu(conv(cas_a, w_cas2)) -> d_out
    hipLaunchKernelGGL((conv3x3_kernel<64,64,false,1,false,false>), grd, blk, 0, stream,
        buf1, nullptr, w_cas2, b_cas2, nullptr, nullptr, outp, H, W, 64);

    // 6. pack2 per batch: om = conv(off2[b], w_om2) -> buf1 ; feat3[b] = lrelu(mdcn(feat2[b])) -> d_out[b]
    //    (off2[b] slice is dead once its om conv ran; feat2 stays live in buf0)
    for (int b = 0; b < B; ++b) {
        hipLaunchKernelGGL((conv3x3_kernel<64,72,false,0,false,false>), grd3, blk, 0, stream,
            outp + b * chw, nullptr, w_om2, b_om2, nullptr, nullptr, buf1, H, W, 216);
        hipLaunchKernelGGL((mdcn_kernel<1>), grd1, blk, 0, stream,
            buf0 + b * chw, buf1, w_dcn2, b_dcn2, outp + b * chw, H, W);
    }

    // 7. emb_ref = conv(ref, w_ta1) -> buf1 ; emb = conv(feat3, w_ta2) -> buf0 ; corr = dot
    hipLaunchKernelGGL((conv3x3_kernel<64,64,false,0,false,false>), grd, blk, 0, stream,
        ref, nullptr, w_ta1, b_ta1, nullptr, nullptr, buf1, H, W, 64);
    hipLaunchKernelGGL((conv3x3_kernel<64,64,false,0,false,false>), grd, blk, 0, stream,
        outp, nullptr, w_ta2, b_ta2, nullptr, nullptr, buf0, H, W, 64);
    {
        int total = (int)(B * HWp);
        int nb = (total + 255) / 256;
        hipLaunchKernelGGL(dot64_kernel, dim3(nb), blk, 0, stream,
            buf1, buf0, corr, (int)HWp, B);
    }

    // 8. out = lrelu(conv(ref * corr, w_ff)) + ref -> d_out
    hipLaunchKernelGGL((conv3x3_kernel<64,64,false,1,true,true>), grd, blk, 0, stream,
        ref, nullptr, w_ff, b_ff, corr, ref, outp, H, W, 64);
}

// Round 2
// 1432.849 us; speedup vs baseline: 6.1345x; 6.1345x over previous
//
#include <hip/hip_runtime.h>
#include <cmath>

// fusion_36455682409119 round 2: bf16 MFMA implicit-GEMM convs + phased MFMA mdcn.
// Internal activation layout: NHWC bf16 ([B][H][W][C], C contiguous).
// Weights prepacked to [chunk][j][cs][64oc][32k] bf16 (A-frag coalesced).
// ws layout: S0=ref_t S1=neb_t/corr/ffw S2 S3 (29.49MB each) [+ om tail if fits]
// d_out layout (scratch until final): [om slot0][om slot1][packed weights]

using short8 = __attribute__((ext_vector_type(8))) short;
using f32x4  = __attribute__((ext_vector_type(4))) float;

#define DEVINL static __device__ __forceinline__

DEVINL unsigned short f2bf(float f){
    unsigned u = __float_as_uint(f);
    u += 0x7fffu + ((u >> 16) & 1u);
    return (unsigned short)(u >> 16);
}
DEVINL unsigned pack2(float a, float b){ return (unsigned)f2bf(a) | ((unsigned)f2bf(b) << 16); }
DEVINL float bflo(unsigned u){ return __uint_as_float(u << 16); }
DEVINL float bfhi(unsigned u){ return __uint_as_float(u & 0xffff0000u); }
DEVINL float bf2f(unsigned short u){ return __uint_as_float((unsigned)u << 16); }
DEVINL float lrelu_f(float v){ return v >= 0.f ? v : 0.1f * v; }

// ---------------- NCHW f32 -> NHWC bf16 transpose (C=64) ----------------
__global__ __launch_bounds__(256) void nchw2nhwc(const float* __restrict__ in,
                                                 unsigned short* __restrict__ out)
{
    constexpr int HW = 180 * 320;
    size_t idx = (size_t)blockIdx.x * 256 + threadIdx.x;   // pixel id over B*HW (exact grid)
    size_t bb = idx / HW, p = idx % HW;
    const float* src = in + (bb * 64) * (size_t)HW + p;    // coalesced per-c iteration
    unsigned short* dst = out + idx * 64;
    #pragma unroll
    for (int c0 = 0; c0 < 64; c0 += 16) {
        unsigned r[8];
        #pragma unroll
        for (int q = 0; q < 8; ++q)
            r[q] = pack2(src[(size_t)(c0 + 2*q) * HW], src[(size_t)(c0 + 2*q + 1) * HW]);
        *(uint4*)(dst + c0)     = *(uint4*)&r[0];
        *(uint4*)(dst + c0 + 8) = *(uint4*)&r[4];
    }
}

// ---------------- weight prepack: conv order [ch][j][cs][64oc][32k], k=c ----------------
__global__ __launch_bounds__(256) void prep_conv_w(const float* __restrict__ w,
                                                   unsigned short* __restrict__ dst,
                                                   int COUT, int CIN, int total)
{
    int idx = blockIdx.x * 256 + threadIdx.x;
    if (idx >= total) return;
    int ncs = CIN / 32;
    int kk = idx & 31, oc_l = (idx >> 5) & 63, rest = idx >> 11;
    int cs = rest % ncs; int rest2 = rest / ncs;
    int j = rest2 % 9; int ch = rest2 / 9;
    int oc = ch * 64 + oc_l, c = cs * 32 + kk;
    float v = (oc < COUT) ? w[((size_t)oc * CIN + c) * 9 + j] : 0.f;
    dst[idx] = f2bf(v);
}

// mdcn order: [s(18)][64oc][32k], k_lin = (g*9+tap)*8 + c_in_group
__global__ __launch_bounds__(256) void prep_dcn_w(const float* __restrict__ w,
                                                  unsigned short* __restrict__ dst)
{
    int idx = blockIdx.x * 256 + threadIdx.x;   // total 36864, grid exact
    int kk = idx & 31, oc = (idx >> 5) & 63, s = idx >> 11;
    int k = s * 32 + kk;
    int gt = k >> 3, c8 = k & 7;
    int g = gt / 9, tp = gt - g * 9;
    dst[idx] = f2bf(w[((size_t)oc * 64 + g * 8 + c8) * 9 + tp]);
}

// ---------------- MFMA conv 3x3 SAME, tile 64oc x (4row x 32col) ----------------
// OUTMODE 0: bf16 NHWC (stride 64). 1: bf16 NHWC stride COUT(216), masked, b=0.
// 2: f32 NCHW out = lrelu(conv)+res.
template<int CIN, bool TWO_IN, bool ACT, bool SCALE, int OUTMODE>
__global__ __launch_bounds__(256, 2) void conv_mfma(
    const unsigned short* __restrict__ in0, const unsigned short* __restrict__ in1,
    const unsigned short* __restrict__ wgt, const float* __restrict__ bias,
    unsigned short* __restrict__ out, const float* __restrict__ corr,
    const float* __restrict__ res, float* __restrict__ outf, int COUT)
{
    constexpr int H = 180, W = 320, HW = H * W;
    constexpr int NCB = CIN / 8;    // 16B c-blocks per pixel
    constexpr int NCS = CIN / 32;   // k-steps per tap
    __shared__ __align__(16) unsigned char lds[6 * 34 * CIN * 2];

    const int tid = threadIdx.x;
    const int b  = (OUTMODE == 1) ? 0 : blockIdx.z;
    const int ch = (OUTMODE == 1) ? blockIdx.z : 0;
    const int x0 = blockIdx.x * 32, y0 = blockIdx.y * 4;

    // stage 6x34 halo, bf16, XOR-swizzled 16B c-blocks (conflict-free ds_read_b128 later)
    for (int t = tid; t < 6 * 34 * NCB; t += 256) {
        int cb = t % NCB; int r = t / NCB;
        int xp = r % 34, yp = r / 34;
        int gx = x0 - 1 + xp, gy = y0 - 1 + yp;
        uint4 v = make_uint4(0, 0, 0, 0);
        if (gx >= 0 && gx < W && gy >= 0 && gy < H) {
            size_t pix = (size_t)b * HW + (size_t)gy * W + gx;
            const unsigned short* src;
            if (TWO_IN) src = (cb < 8) ? (in0 + pix * 64 + cb * 8) : (in1 + pix * 64 + (cb - 8) * 8);
            else        src = in0 + pix * CIN + cb * 8;
            v = *(const uint4*)src;
            if (SCALE) {
                float cv = corr[pix];
                v.x = pack2(bflo(v.x) * cv, bfhi(v.x) * cv);
                v.y = pack2(bflo(v.y) * cv, bfhi(v.y) * cv);
                v.z = pack2(bflo(v.z) * cv, bfhi(v.z) * cv);
                v.w = pack2(bflo(v.w) * cv, bfhi(v.w) * cv);
            }
        }
        int blk = cb ^ (xp & 7);
        *(uint4*)&lds[(size_t)((yp * 34 + xp) * NCB + blk) * 16] = v;
    }
    __syncthreads();

    const int wv = tid >> 6, lane = tid & 63;
    const int ll = lane & 15, lh = lane >> 4;
    const unsigned short* wchunk = wgt + (size_t)ch * (9 * NCS * 2048);
    const int alane = ll * 32 + lh * 8;

    f32x4 acc[4][2];
    #pragma unroll
    for (int mi = 0; mi < 4; ++mi)
        #pragma unroll
        for (int nf = 0; nf < 2; ++nf) acc[mi][nf] = f32x4{0.f, 0.f, 0.f, 0.f};

    #pragma unroll
    for (int j = 0; j < 9; ++j) {
        const int jy = j / 3, jx = j % 3;
        #pragma unroll
        for (int cs = 0; cs < NCS; ++cs) {
            const int s = j * NCS + cs;
            short8 a[4];
            #pragma unroll
            for (int mi = 0; mi < 4; ++mi)
                a[mi] = *(const short8*)(wchunk + (size_t)s * 2048 + mi * 512 + alane);
            short8 bf[2];
            #pragma unroll
            for (int nf = 0; nf < 2; ++nf) {
                int xp = nf * 16 + ll + jx;
                int blk = (cs * 4 + lh) ^ (xp & 7);
                int addr = (((wv + jy) * 34 + xp) * NCB + blk) * 16;
                bf[nf] = *(const short8*)&lds[addr];
            }
            #pragma unroll
            for (int mi = 0; mi < 4; ++mi)
                #pragma unroll
                for (int nf = 0; nf < 2; ++nf)
                    acc[mi][nf] = __builtin_amdgcn_mfma_f32_16x16x32_bf16(a[mi], bf[nf], acc[mi][nf], 0, 0, 0);
        }
    }

    const int py = y0 + wv;
    const size_t pixrow = (size_t)b * HW + (size_t)py * W;
    #pragma unroll
    for (int nf = 0; nf < 2; ++nf) {
        const int px = x0 + nf * 16 + ll;
        #pragma unroll
        for (int mi = 0; mi < 4; ++mi) {
            const int oc_l = mi * 16 + lh * 4;
            if (OUTMODE == 0) {
                float v[4];
                #pragma unroll
                for (int jj = 0; jj < 4; ++jj) {
                    float t = acc[mi][nf][jj] + bias[oc_l + jj];
                    v[jj] = ACT ? lrelu_f(t) : t;
                }
                uint2 st; st.x = pack2(v[0], v[1]); st.y = pack2(v[2], v[3]);
                *(uint2*)&out[(pixrow + px) * 64 + oc_l] = st;
            } else if (OUTMODE == 1) {
                #pragma unroll
                for (int jj = 0; jj < 4; ++jj) {
                    int ocg = ch * 64 + oc_l + jj;
                    if (ocg < COUT) {
                        float t = acc[mi][nf][jj] + bias[ocg];
                        out[(pixrow + px) * (size_t)COUT + ocg] = f2bf(ACT ? lrelu_f(t) : t);
                    }
                }
            } else {
                #pragma unroll
                for (int jj = 0; jj < 4; ++jj) {
                    int oc = oc_l + jj;
                    float t = acc[mi][nf][jj] + bias[oc];
                    if (ACT) t = lrelu_f(t);
                    size_t idx = ((size_t)b * 64 + oc) * HW + (size_t)py * W + px;
                    outf[idx] = t + res[idx];
                }
            }
        }
    }
}

// ---------------- mdcn v2 (dg=8, Cg=8, 64->64): sample->LDS im2col, then MFMA ----------------
// x, om, out are NHWC bf16 per-batch bases; blockIdx.z selects batch via strides.
template<int ACT>
__global__ __launch_bounds__(256, 2) void mdcn_mfma(
    const unsigned short* __restrict__ x, size_t xstride,
    const unsigned short* __restrict__ om, size_t omstride,
    const unsigned short* __restrict__ wgt, const float* __restrict__ bias,
    unsigned short* __restrict__ out, size_t ostride)
{
    constexpr int H = 180, W = 320;
    __shared__ __align__(16) unsigned char sv[72 * 32 * 16];   // [tap_lin][px][8c] bf16

    const int tid = threadIdx.x;
    const unsigned short* xb  = x  + (size_t)blockIdx.z * xstride;
    const unsigned short* omb = om + (size_t)blockIdx.z * omstride;
    unsigned short* ob        = out + (size_t)blockIdx.z * ostride;
    const int px0 = blockIdx.x * 32;
    const int py  = blockIdx.y;

    // phase 1: sampling. thread = (px in tile, group g); 9 taps each.
    {
        const int pxl = tid & 31, g = tid >> 5;
        const int px = px0 + pxl;
        const size_t pixo = ((size_t)py * W + px) * 216;
        #pragma unroll
        for (int k = 0; k < 9; ++k) {
            float oy = bf2f(omb[pixo + g * 9 + k]);
            float ox = bf2f(omb[pixo + 72 + g * 9 + k]);
            float mr = bf2f(omb[pixo + 144 + g * 9 + k]);
            float m = 1.f / (1.f + __expf(-mr));
            float pyf = (float)(py + (k / 3) - 1) + oy;
            float pxf = (float)(px + (k % 3) - 1) + ox;
            float y0f = floorf(pyf), x0f = floorf(pxf);
            float wy = pyf - y0f, wx = pxf - x0f;
            int yi = (int)y0f, xi = (int)x0f;
            bool vy0 = (yi >= 0) && (yi < H);
            bool vy1 = (yi + 1 >= 0) && (yi + 1 < H);
            bool vx0 = (xi >= 0) && (xi < W);
            bool vx1 = (xi + 1 >= 0) && (xi + 1 < W);
            float w00 = (vy0 && vx0) ? (1.f - wy) * (1.f - wx) * m : 0.f;
            float w01 = (vy0 && vx1) ? (1.f - wy) * wx * m : 0.f;
            float w10 = (vy1 && vx0) ? wy * (1.f - wx) * m : 0.f;
            float w11 = (vy1 && vx1) ? wy * wx * m : 0.f;
            int yc0 = min(max(yi, 0), H - 1), yc1 = min(max(yi + 1, 0), H - 1);
            int xc0 = min(max(xi, 0), W - 1), xc1 = min(max(xi + 1, 0), W - 1);
            uint4 c00 = *(const uint4*)(xb + ((size_t)(yc0 * W + xc0) * 64 + g * 8));
            uint4 c01 = *(const uint4*)(xb + ((size_t)(yc0 * W + xc1) * 64 + g * 8));
            uint4 c10 = *(const uint4*)(xb + ((size_t)(yc1 * W + xc0) * 64 + g * 8));
            uint4 c11 = *(const uint4*)(xb + ((size_t)(yc1 * W + xc1) * 64 + g * 8));
            const unsigned* p00 = (const unsigned*)&c00;
            const unsigned* p01 = (const unsigned*)&c01;
            const unsigned* p10 = (const unsigned*)&c10;
            const unsigned* p11 = (const unsigned*)&c11;
            unsigned r[4];
            #pragma unroll
            for (int q = 0; q < 4; ++q) {
                float lo = w00 * bflo(p00[q]) + w01 * bflo(p01[q]) + w10 * bflo(p10[q]) + w11 * bflo(p11[q]);
                float hi = w00 * bfhi(p00[q]) + w01 * bfhi(p01[q]) + w10 * bfhi(p10[q]) + w11 * bfhi(p11[q]);
                r[q] = pack2(lo, hi);
            }
            *(uint4*)&sv[(size_t)((g * 9 + k) * 32 + pxl) * 16] = *(uint4*)r;
        }
    }
    __syncthreads();

    // phase 2: MFMA. wave wv -> 16 oc, both 16-px n-frags, K=576 (18 steps).
    const int wv = tid >> 6, lane = tid & 63;
    const int ll = lane & 15, lh = lane >> 4;
    f32x4 acc[2] = {f32x4{0.f,0.f,0.f,0.f}, f32x4{0.f,0.f,0.f,0.f}};
    #pragma unroll
    for (int s = 0; s < 18; ++s) {
        short8 a = *(const short8*)(wgt + (size_t)(s * 64 + wv * 16 + ll) * 32 + lh * 8);
        #pragma unroll
        for (int nf = 0; nf < 2; ++nf) {
            short8 bb = *(const short8*)&sv[(size_t)s * 2048 + lh * 512 + (nf * 16 + ll) * 16];
            acc[nf] = __builtin_amdgcn_mfma_f32_16x16x32_bf16(a, bb, acc[nf], 0, 0, 0);
        }
    }
    #pragma unroll
    for (int nf = 0; nf < 2; ++nf) {
        int px = px0 + nf * 16 + ll;
        int oc0 = wv * 16 + lh * 4;
        float v[4];
        #pragma unroll
        for (int jj = 0; jj < 4; ++jj) {
            float t = acc[nf][jj] + bias[oc0 + jj];
            v[jj] = ACT ? lrelu_f(t) : t;
        }
        uint2 st; st.x = pack2(v[0], v[1]); st.y = pack2(v[2], v[3]);
        *(uint2*)&ob[((size_t)py * W + px) * 64 + oc0] = st;
    }
}

// ---------------- corr = sum_c emb*emb_ref ----------------
__global__ __launch_bounds__(256) void corr_dot(const unsigned short* __restrict__ a,
                                                const unsigned short* __restrict__ b,
                                                float* __restrict__ out, int total)
{
    int idx = blockIdx.x * 256 + threadIdx.x;
    if (idx >= total) return;
    const unsigned* pa = (const unsigned*)(a + (size_t)idx * 64);
    const unsigned* pb = (const unsigned*)(b + (size_t)idx * 64);
    float s = 0.f;
    #pragma unroll
    for (int q = 0; q < 32; ++q)
        s += bflo(pa[q]) * bflo(pb[q]) + bfhi(pa[q]) * bfhi(pb[q]);
    out[idx] = s;
}

extern "C" void kernel_launch(void* const* d_in, const int* in_sizes, int n_in,
                              void* d_out, int out_size, void* d_ws, size_t ws_size,
                              hipStream_t stream)
{
    const float* ref    = (const float*)d_in[0];
    const float* neb    = (const float*)d_in[1];
    const float* w_oc1  = (const float*)d_in[2];  const float* b_oc1  = (const float*)d_in[3];
    const float* w_om1  = (const float*)d_in[4];  const float* b_om1  = (const float*)d_in[5];
    const float* w_dcn1 = (const float*)d_in[6];  const float* b_dcn1 = (const float*)d_in[7];
    const float* w_fc   = (const float*)d_in[8];  const float* b_fc   = (const float*)d_in[9];
    const float* w_cas1 = (const float*)d_in[10]; const float* b_cas1 = (const float*)d_in[11];
    const float* w_cas2 = (const float*)d_in[12]; const float* b_cas2 = (const float*)d_in[13];
    const float* w_om2  = (const float*)d_in[14]; const float* b_om2  = (const float*)d_in[15];
    const float* w_dcn2 = (const float*)d_in[16]; const float* b_dcn2 = (const float*)d_in[17];
    const float* w_ta1  = (const float*)d_in[18]; const float* b_ta1  = (const float*)d_in[19];
    const float* w_ta2  = (const float*)d_in[20]; const float* b_ta2  = (const float*)d_in[21];
    const float* w_ff   = (const float*)d_in[22]; const float* b_ff   = (const float*)d_in[23];

    constexpr int H = 180, W = 320, HW = H * W;
    constexpr size_t CHW = (size_t)HW * 64;              // els per batch slice
    constexpr size_t SLB = 4 * CHW * 2;                  // slot bytes (29,491,200)
    constexpr size_t OMSLOT_EL = (size_t)HW * 216;       // om els per batch
    constexpr size_t OMSLOT_B  = OMSLOT_EL * 2;

    char* wsb = (char*)d_ws;
    unsigned short* S0 = (unsigned short*)(wsb);             // ref_t
    unsigned short* S1 = (unsigned short*)(wsb + SLB);       // neb_t -> cas_a -> feat3 -> corr/ffw
    unsigned short* S2 = (unsigned short*)(wsb + 2 * SLB);   // off1 -> feat2 -> emb_ref
    unsigned short* S3 = (unsigned short*)(wsb + 3 * SLB);   // feat1 -> off2 -> emb
    float* corrf = (float*)S1;
    unsigned short* ffw = (unsigned short*)(wsb + SLB + (2u << 20));

    char* doutb = (char*)d_out;
    unsigned short* omA0 = (unsigned short*)doutb;
    unsigned short* omA1 = omA0 + OMSLOT_EL;
    unsigned short* wb   = (unsigned short*)(doutb + 2 * OMSLOT_B);  // packed weights (~1.4MB, d_out tail)
    const bool big = ws_size >= 4 * SLB + 2 * OMSLOT_B;
    unsigned short* omB0 = (unsigned short*)(wsb + 4 * SLB);
    unsigned short* omB1 = omB0 + OMSLOT_EL;

    unsigned short* w_oc1p = wb + 0;
    unsigned short* w_om1p = wb + 73728;
    unsigned short* w_dcn1p= wb + 221184;
    unsigned short* w_fcp  = wb + 258048;
    unsigned short* w_cas1p= wb + 294912;
    unsigned short* w_cas2p= wb + 368640;
    unsigned short* w_om2p = wb + 405504;
    unsigned short* w_dcn2p= wb + 552960;
    unsigned short* w_ta1p = wb + 589824;
    unsigned short* w_ta2p = wb + 626688;
    unsigned short* w_ffp  = wb + 663552;

    dim3 blk(256);
    dim3 g4(10, 45, 4);
    dim3 gm(10, 180, 2);

    // transposes + weight prep
    nchw2nhwc<<<900, blk, 0, stream>>>(ref, S0);
    nchw2nhwc<<<900, blk, 0, stream>>>(neb, S1);
    auto PCW = [&](const float* src, unsigned short* dst, int cout, int cin, int nch){
        int total = nch * 9 * (cin / 32) * 2048;
        prep_conv_w<<<(total + 255) / 256, blk, 0, stream>>>(src, dst, cout, cin, total);
    };
    PCW(w_oc1, w_oc1p, 64, 128, 1);
    PCW(w_om1, w_om1p, 216, 64, 4);
    prep_dcn_w<<<144, blk, 0, stream>>>(w_dcn1, w_dcn1p);
    PCW(w_fc,  w_fcp,  64, 64, 1);
    PCW(w_cas1, w_cas1p, 64, 128, 1);
    PCW(w_cas2, w_cas2p, 64, 64, 1);
    PCW(w_om2, w_om2p, 216, 64, 4);
    prep_dcn_w<<<144, blk, 0, stream>>>(w_dcn2, w_dcn2p);
    PCW(w_ta1, w_ta1p, 64, 64, 1);
    PCW(w_ta2, w_ta2p, 64, 64, 1);
    PCW(w_ff,  w_ffp,  64, 64, 1);

    // 1. off1 = lrelu(conv(concat(neb,ref))) -> S2
    conv_mfma<128, true, true, false, 0><<<g4, blk, 0, stream>>>(
        S1, S0, w_oc1p, b_oc1, S2, nullptr, nullptr, nullptr, 64);

    auto omconv = [&](const unsigned short* inp, const unsigned short* wp, const float* bp,
                      unsigned short* slot){
        conv_mfma<64, false, false, false, 1><<<g4, blk, 0, stream>>>(
            inp, nullptr, wp, bp, slot, nullptr, nullptr, nullptr, 216);
    };

    // 2. pack1: om1 = conv(off1); feat1 = mdcn(neb_t, om1) -> S3
    if (big) {
        omconv(S2 + 0 * CHW, w_om1p, b_om1, omA0);
        omconv(S2 + 1 * CHW, w_om1p, b_om1, omA1);
        omconv(S2 + 2 * CHW, w_om1p, b_om1, omB0);
        omconv(S2 + 3 * CHW, w_om1p, b_om1, omB1);
        mdcn_mfma<0><<<gm, blk, 0, stream>>>(S1, CHW, omA0, OMSLOT_EL, w_dcn1p, b_dcn1, S3, CHW);
        mdcn_mfma<0><<<gm, blk, 0, stream>>>(S1 + 2 * CHW, CHW, omB0, OMSLOT_EL, w_dcn1p, b_dcn1, S3 + 2 * CHW, CHW);
    } else {
        for (int p = 0; p < 2; ++p) {
            omconv(S2 + (2 * p) * CHW, w_om1p, b_om1, omA0);
            omconv(S2 + (2 * p + 1) * CHW, w_om1p, b_om1, omA1);
            mdcn_mfma<0><<<gm, blk, 0, stream>>>(S1 + 2 * p * CHW, CHW, omA0, OMSLOT_EL,
                                                 w_dcn1p, b_dcn1, S3 + 2 * p * CHW, CHW);
        }
    }

    // 3. feat2 = lrelu(conv(feat1)) -> S2
    conv_mfma<64, false, true, false, 0><<<g4, blk, 0, stream>>>(
        S3, nullptr, w_fcp, b_fc, S2, nullptr, nullptr, nullptr, 64);
    // 4. cas_a = lrelu(conv(concat(feat2,ref))) -> S1
    conv_mfma<128, true, true, false, 0><<<g4, blk, 0, stream>>>(
        S2, S0, w_cas1p, b_cas1, S1, nullptr, nullptr, nullptr, 64);
    // 5. off2 = lrelu(conv(cas_a)) -> S3
    conv_mfma<64, false, true, false, 0><<<g4, blk, 0, stream>>>(
        S1, nullptr, w_cas2p, b_cas2, S3, nullptr, nullptr, nullptr, 64);

    // 6. pack2: om2 = conv(off2); feat3 = lrelu(mdcn(feat2, om2)) -> S1
    if (big) {
        omconv(S3 + 0 * CHW, w_om2p, b_om2, omA0);
        omconv(S3 + 1 * CHW, w_om2p, b_om2, omA1);
        omconv(S3 + 2 * CHW, w_om2p, b_om2, omB0);
        omconv(S3 + 3 * CHW, w_om2p, b_om2, omB1);
        mdcn_mfma<1><<<gm, blk, 0, stream>>>(S2, CHW, omA0, OMSLOT_EL, w_dcn2p, b_dcn2, S1, CHW);
        mdcn_mfma<1><<<gm, blk, 0, stream>>>(S2 + 2 * CHW, CHW, omB0, OMSLOT_EL, w_dcn2p, b_dcn2, S1 + 2 * CHW, CHW);
    } else {
        for (int p = 0; p < 2; ++p) {
            omconv(S3 + (2 * p) * CHW, w_om2p, b_om2, omA0);
            omconv(S3 + (2 * p + 1) * CHW, w_om2p, b_om2, omA1);
            mdcn_mfma<1><<<gm, blk, 0, stream>>>(S2 + 2 * p * CHW, CHW, omA0, OMSLOT_EL,
                                                 w_dcn2p, b_dcn2, S1 + 2 * p * CHW, CHW);
        }
    }

    // 7. emb_ref = conv(ref_t, ta1) -> S2 ; emb = conv(feat3, ta2) -> S3 ; corr -> S1
    conv_mfma<64, false, false, false, 0><<<g4, blk, 0, stream>>>(
        S0, nullptr, w_ta1p, b_ta1, S2, nullptr, nullptr, nullptr, 64);
    conv_mfma<64, false, false, false, 0><<<g4, blk, 0, stream>>>(
        S1, nullptr, w_ta2p, b_ta2, S3, nullptr, nullptr, nullptr, 64);
    corr_dot<<<900, blk, 0, stream>>>(S2, S3, corrf, 4 * HW);

    // relocate ff weights out of d_out before the final conv overwrites it
    hipMemcpyAsync(ffw, w_ffp, 36864 * 2, hipMemcpyDeviceToDevice, stream);

    // 8. out = lrelu(conv(ref_t*corr, ff)) + ref  (f32 NCHW into d_out)
    conv_mfma<64, false, true, true, 2><<<g4, blk, 0, stream>>>(
        S0, nullptr, ffw, b_ff, nullptr, corrf, ref, (float*)d_out, 64);
}

// Round 3
// 1378.475 us; speedup vs baseline: 6.3765x; 1.0394x over previous
//
#include <hip/hip_runtime.h>
#include <cmath>

// fusion_36455682409119 round 3:
//  - mdcn: planar om layout [216][HW], tap-split halves (18KB LDS, launch_bounds(256,8))
//  - om conv: planar coalesced stores
//  - corr fused into ta2 conv epilogue (shfl_xor reduce over oc quarters)
//  - conv occupancy: launch_bounds(256,3) for CIN=64, (256,2) for CIN=128

using short8 = __attribute__((ext_vector_type(8))) short;
using f32x4  = __attribute__((ext_vector_type(4))) float;

#define DEVINL static __device__ __forceinline__

DEVINL unsigned short f2bf(float f){
    unsigned u = __float_as_uint(f);
    u += 0x7fffu + ((u >> 16) & 1u);
    return (unsigned short)(u >> 16);
}
DEVINL unsigned pack2(float a, float b){ return (unsigned)f2bf(a) | ((unsigned)f2bf(b) << 16); }
DEVINL float bflo(unsigned u){ return __uint_as_float(u << 16); }
DEVINL float bfhi(unsigned u){ return __uint_as_float(u & 0xffff0000u); }
DEVINL float bf2f(unsigned short u){ return __uint_as_float((unsigned)u << 16); }
DEVINL float lrelu_f(float v){ return v >= 0.f ? v : 0.1f * v; }

// ---------------- NCHW f32 -> NHWC bf16 transpose (C=64) ----------------
__global__ __launch_bounds__(256) void nchw2nhwc(const float* __restrict__ in,
                                                 unsigned short* __restrict__ out)
{
    constexpr int HW = 180 * 320;
    size_t idx = (size_t)blockIdx.x * 256 + threadIdx.x;
    size_t bb = idx / HW, p = idx % HW;
    const float* src = in + (bb * 64) * (size_t)HW + p;
    unsigned short* dst = out + idx * 64;
    #pragma unroll
    for (int c0 = 0; c0 < 64; c0 += 16) {
        unsigned r[8];
        #pragma unroll
        for (int q = 0; q < 8; ++q)
            r[q] = pack2(src[(size_t)(c0 + 2*q) * HW], src[(size_t)(c0 + 2*q + 1) * HW]);
        *(uint4*)(dst + c0)     = *(uint4*)&r[0];
        *(uint4*)(dst + c0 + 8) = *(uint4*)&r[4];
    }
}

// ---------------- weight prepack: conv order [ch][j][cs][64oc][32k], k=c ----------------
__global__ __launch_bounds__(256) void prep_conv_w(const float* __restrict__ w,
                                                   unsigned short* __restrict__ dst,
                                                   int COUT, int CIN, int total)
{
    int idx = blockIdx.x * 256 + threadIdx.x;
    if (idx >= total) return;
    int ncs = CIN / 32;
    int kk = idx & 31, oc_l = (idx >> 5) & 63, rest = idx >> 11;
    int cs = rest % ncs; int rest2 = rest / ncs;
    int j = rest2 % 9; int ch = rest2 / 9;
    int oc = ch * 64 + oc_l, c = cs * 32 + kk;
    float v = (oc < COUT) ? w[((size_t)oc * CIN + c) * 9 + j] : 0.f;
    dst[idx] = f2bf(v);
}

// mdcn order: [s(18)][64oc][32k], k_lin = (g*9+tap)*8 + c_in_group
__global__ __launch_bounds__(256) void prep_dcn_w(const float* __restrict__ w,
                                                  unsigned short* __restrict__ dst)
{
    int idx = blockIdx.x * 256 + threadIdx.x;   // total 36864
    int kk = idx & 31, oc = (idx >> 5) & 63, s = idx >> 11;
    int k = s * 32 + kk;
    int gt = k >> 3, c8 = k & 7;
    int g = gt / 9, tp = gt - g * 9;
    dst[idx] = f2bf(w[((size_t)oc * 64 + g * 8 + c8) * 9 + tp]);
}

// ---------------- MFMA conv 3x3 SAME, tile 64oc x (4row x 32col) ----------------
// OUTMODE 0: bf16 NHWC (stride 64). 1: bf16 PLANAR [COUT][HW], masked, b=0.
// 2: f32 NCHW out = lrelu(conv)+res. 3: corr fused — dot(conv_out, in1) -> outf f32.
template<int CIN, bool TWO_IN, bool ACT, bool SCALE, int OUTMODE>
__global__ __launch_bounds__(256, (CIN == 128 ? 2 : 3)) void conv_mfma(
    const unsigned short* __restrict__ in0, const unsigned short* __restrict__ in1,
    const unsigned short* __restrict__ wgt, const float* __restrict__ bias,
    unsigned short* __restrict__ out, const float* __restrict__ corr,
    const float* __restrict__ res, float* __restrict__ outf, int COUT)
{
    constexpr int H = 180, W = 320, HW = H * W;
    constexpr int NCB = CIN / 8;    // 16B c-blocks per pixel
    constexpr int NCS = CIN / 32;   // k-steps per tap
    __shared__ __align__(16) unsigned char lds[6 * 34 * CIN * 2];

    const int tid = threadIdx.x;
    const int b  = (OUTMODE == 1) ? 0 : blockIdx.z;
    const int ch = (OUTMODE == 1) ? blockIdx.z : 0;
    const int x0 = blockIdx.x * 32, y0 = blockIdx.y * 4;

    // stage 6x34 halo, bf16, XOR-swizzled 16B c-blocks
    for (int t = tid; t < 6 * 34 * NCB; t += 256) {
        int cb = t % NCB; int r = t / NCB;
        int xp = r % 34, yp = r / 34;
        int gx = x0 - 1 + xp, gy = y0 - 1 + yp;
        uint4 v = make_uint4(0, 0, 0, 0);
        if (gx >= 0 && gx < W && gy >= 0 && gy < H) {
            size_t pix = (size_t)b * HW + (size_t)gy * W + gx;
            const unsigned short* src;
            if (TWO_IN) src = (cb < 8) ? (in0 + pix * 64 + cb * 8) : (in1 + pix * 64 + (cb - 8) * 8);
            else        src = in0 + pix * CIN + cb * 8;
            v = *(const uint4*)src;
            if (SCALE) {
                float cv = corr[pix];
                v.x = pack2(bflo(v.x) * cv, bfhi(v.x) * cv);
                v.y = pack2(bflo(v.y) * cv, bfhi(v.y) * cv);
                v.z = pack2(bflo(v.z) * cv, bfhi(v.z) * cv);
                v.w = pack2(bflo(v.w) * cv, bfhi(v.w) * cv);
            }
        }
        int blk = cb ^ (xp & 7);
        *(uint4*)&lds[(size_t)((yp * 34 + xp) * NCB + blk) * 16] = v;
    }
    __syncthreads();

    const int wv = tid >> 6, lane = tid & 63;
    const int ll = lane & 15, lh = lane >> 4;
    const unsigned short* wchunk = wgt + (size_t)ch * (9 * NCS * 2048);
    const int alane = ll * 32 + lh * 8;

    f32x4 acc[4][2];
    #pragma unroll
    for (int mi = 0; mi < 4; ++mi)
        #pragma unroll
        for (int nf = 0; nf < 2; ++nf) acc[mi][nf] = f32x4{0.f, 0.f, 0.f, 0.f};

    #pragma unroll
    for (int j = 0; j < 9; ++j) {
        const int jy = j / 3, jx = j % 3;
        #pragma unroll
        for (int cs = 0; cs < NCS; ++cs) {
            const int s = j * NCS + cs;
            short8 a[4];
            #pragma unroll
            for (int mi = 0; mi < 4; ++mi)
                a[mi] = *(const short8*)(wchunk + (size_t)s * 2048 + mi * 512 + alane);
            short8 bf[2];
            #pragma unroll
            for (int nf = 0; nf < 2; ++nf) {
                int xp = nf * 16 + ll + jx;
                int blk = (cs * 4 + lh) ^ (xp & 7);
                int addr = (((wv + jy) * 34 + xp) * NCB + blk) * 16;
                bf[nf] = *(const short8*)&lds[addr];
            }
            #pragma unroll
            for (int mi = 0; mi < 4; ++mi)
                #pragma unroll
                for (int nf = 0; nf < 2; ++nf)
                    acc[mi][nf] = __builtin_amdgcn_mfma_f32_16x16x32_bf16(a[mi], bf[nf], acc[mi][nf], 0, 0, 0);
        }
    }

    const int py = y0 + wv;
    const size_t pixrow = (size_t)b * HW + (size_t)py * W;
    #pragma unroll
    for (int nf = 0; nf < 2; ++nf) {
        const int px = x0 + nf * 16 + ll;
        if (OUTMODE == 3) {
            // fused corr: dot(conv_out + bias, in1[pixel]) over all 64 oc
            float dot = 0.f;
            const unsigned* er = (const unsigned*)(in1 + (pixrow + px) * 64);
            #pragma unroll
            for (int mi = 0; mi < 4; ++mi) {
                const int oc_l = mi * 16 + lh * 4;
                unsigned e0 = er[oc_l / 2], e1 = er[oc_l / 2 + 1];
                float t0 = acc[mi][nf][0] + bias[oc_l + 0];
                float t1 = acc[mi][nf][1] + bias[oc_l + 1];
                float t2 = acc[mi][nf][2] + bias[oc_l + 2];
                float t3 = acc[mi][nf][3] + bias[oc_l + 3];
                dot += t0 * bflo(e0) + t1 * bfhi(e0) + t2 * bflo(e1) + t3 * bfhi(e1);
            }
            dot += __shfl_xor(dot, 16);
            dot += __shfl_xor(dot, 32);
            if (lh == 0) outf[pixrow + px] = dot;
        } else {
            #pragma unroll
            for (int mi = 0; mi < 4; ++mi) {
                const int oc_l = mi * 16 + lh * 4;
                if (OUTMODE == 0) {
                    float v[4];
                    #pragma unroll
                    for (int jj = 0; jj < 4; ++jj) {
                        float t = acc[mi][nf][jj] + bias[oc_l + jj];
                        v[jj] = ACT ? lrelu_f(t) : t;
                    }
                    uint2 st; st.x = pack2(v[0], v[1]); st.y = pack2(v[2], v[3]);
                    *(uint2*)&out[(pixrow + px) * 64 + oc_l] = st;
                } else if (OUTMODE == 1) {
                    #pragma unroll
                    for (int jj = 0; jj < 4; ++jj) {
                        int ocg = ch * 64 + oc_l + jj;
                        if (ocg < COUT) {
                            float t = acc[mi][nf][jj] + bias[ocg];
                            out[(size_t)ocg * HW + (size_t)py * W + px] = f2bf(ACT ? lrelu_f(t) : t);
                        }
                    }
                } else {
                    #pragma unroll
                    for (int jj = 0; jj < 4; ++jj) {
                        int oc = oc_l + jj;
                        float t = acc[mi][nf][jj] + bias[oc];
                        if (ACT) t = lrelu_f(t);
                        size_t idx = ((size_t)b * 64 + oc) * HW + (size_t)py * W + px;
                        outf[idx] = t + res[idx];
                    }
                }
            }
        }
    }
}

// ---------------- mdcn v2 (dg=8, Cg=8, 64->64): tap-split sample->LDS, MFMA ----------------
// om is PLANAR [216][HW] bf16 per batch. Taps processed in 2 halves (groups 0-3, 4-7).
template<int ACT>
__global__ __launch_bounds__(256, 8) void mdcn_mfma(
    const unsigned short* __restrict__ x, size_t xstride,
    const unsigned short* __restrict__ om, size_t omstride,
    const unsigned short* __restrict__ wgt, const float* __restrict__ bias,
    unsigned short* __restrict__ out, size_t ostride)
{
    constexpr int H = 180, W = 320, HW = H * W;
    __shared__ __align__(16) unsigned char sv[36 * 32 * 16];   // 18KB: [tap36][px32][8c]

    const int tid = threadIdx.x;
    const unsigned short* xb  = x  + (size_t)blockIdx.z * xstride;
    const unsigned short* omb = om + (size_t)blockIdx.z * omstride;
    unsigned short* ob        = out + (size_t)blockIdx.z * ostride;
    const int px0 = blockIdx.x * 32;
    const int py  = blockIdx.y;

    const int wv = tid >> 6, lane = tid & 63;
    const int ll = lane & 15, lh = lane >> 4;
    f32x4 acc[2] = {f32x4{0.f,0.f,0.f,0.f}, f32x4{0.f,0.f,0.f,0.f}};

    const int pxl = tid & 31, gg = (tid >> 5) & 3, rep = tid >> 7;
    const int px = px0 + pxl;
    const size_t p = (size_t)py * W + px;
    const int k_begin = rep ? 5 : 0, k_end = rep ? 9 : 5;

    #pragma unroll
    for (int h = 0; h < 2; ++h) {
        const int g = h * 4 + gg;
        for (int k = k_begin; k < k_end; ++k) {
            float oy = bf2f(omb[(size_t)(g * 9 + k) * HW + p]);
            float ox = bf2f(omb[(size_t)(72 + g * 9 + k) * HW + p]);
            float mr = bf2f(omb[(size_t)(144 + g * 9 + k) * HW + p]);
            float m = 1.f / (1.f + __expf(-mr));
            float pyf = (float)(py + (k / 3) - 1) + oy;
            float pxf = (float)(px + (k % 3) - 1) + ox;
            float y0f = floorf(pyf), x0f = floorf(pxf);
            float wy = pyf - y0f, wx = pxf - x0f;
            int yi = (int)y0f, xi = (int)x0f;
            bool vy0 = (yi >= 0) && (yi < H);
            bool vy1 = (yi + 1 >= 0) && (yi + 1 < H);
            bool vx0 = (xi >= 0) && (xi < W);
            bool vx1 = (xi + 1 >= 0) && (xi + 1 < W);
            float w00 = (vy0 && vx0) ? (1.f - wy) * (1.f - wx) * m : 0.f;
            float w01 = (vy0 && vx1) ? (1.f - wy) * wx * m : 0.f;
            float w10 = (vy1 && vx0) ? wy * (1.f - wx) * m : 0.f;
            float w11 = (vy1 && vx1) ? wy * wx * m : 0.f;
            int yc0 = min(max(yi, 0), H - 1), yc1 = min(max(yi + 1, 0), H - 1);
            int xc0 = min(max(xi, 0), W - 1), xc1 = min(max(xi + 1, 0), W - 1);
            uint4 c00 = *(const uint4*)(xb + ((size_t)(yc0 * W + xc0) * 64 + g * 8));
            uint4 c01 = *(const uint4*)(xb + ((size_t)(yc0 * W + xc1) * 64 + g * 8));
            uint4 c10 = *(const uint4*)(xb + ((size_t)(yc1 * W + xc0) * 64 + g * 8));
            uint4 c11 = *(const uint4*)(xb + ((size_t)(yc1 * W + xc1) * 64 + g * 8));
            const unsigned* p00 = (const unsigned*)&c00;
            const unsigned* p01 = (const unsigned*)&c01;
            const unsigned* p10 = (const unsigned*)&c10;
            const unsigned* p11 = (const unsigned*)&c11;
            unsigned r[4];
            #pragma unroll
            for (int q = 0; q < 4; ++q) {
                float lo = w00 * bflo(p00[q]) + w01 * bflo(p01[q]) + w10 * bflo(p10[q]) + w11 * bflo(p11[q]);
                float hi = w00 * bfhi(p00[q]) + w01 * bfhi(p01[q]) + w10 * bfhi(p10[q]) + w11 * bfhi(p11[q]);
                r[q] = pack2(lo, hi);
            }
            *(uint4*)&sv[(size_t)((gg * 9 + k) * 32 + pxl) * 16] = *(uint4*)r;
        }
        __syncthreads();
        #pragma unroll
        for (int s = 0; s < 9; ++s) {
            short8 a = *(const short8*)(wgt + (size_t)((h * 9 + s) * 64 + wv * 16 + ll) * 32 + lh * 8);
            #pragma unroll
            for (int nf = 0; nf < 2; ++nf) {
                short8 bb = *(const short8*)&sv[(size_t)s * 2048 + lh * 512 + (nf * 16 + ll) * 16];
                acc[nf] = __builtin_amdgcn_mfma_f32_16x16x32_bf16(a, bb, acc[nf], 0, 0, 0);
            }
        }
        __syncthreads();
    }

    #pragma unroll
    for (int nf = 0; nf < 2; ++nf) {
        int opx = px0 + nf * 16 + ll;
        int oc0 = wv * 16 + lh * 4;
        float v[4];
        #pragma unroll
        for (int jj = 0; jj < 4; ++jj) {
            float t = acc[nf][jj] + bias[oc0 + jj];
            v[jj] = ACT ? lrelu_f(t) : t;
        }
        uint2 st; st.x = pack2(v[0], v[1]); st.y = pack2(v[2], v[3]);
        *(uint2*)&ob[((size_t)py * W + opx) * 64 + oc0] = st;
    }
}

extern "C" void kernel_launch(void* const* d_in, const int* in_sizes, int n_in,
                              void* d_out, int out_size, void* d_ws, size_t ws_size,
                              hipStream_t stream)
{
    const float* ref    = (const float*)d_in[0];
    const float* neb    = (const float*)d_in[1];
    const float* w_oc1  = (const float*)d_in[2];  const float* b_oc1  = (const float*)d_in[3];
    const float* w_om1  = (const float*)d_in[4];  const float* b_om1  = (const float*)d_in[5];
    const float* w_dcn1 = (const float*)d_in[6];  const float* b_dcn1 = (const float*)d_in[7];
    const float* w_fc   = (const float*)d_in[8];  const float* b_fc   = (const float*)d_in[9];
    const float* w_cas1 = (const float*)d_in[10]; const float* b_cas1 = (const float*)d_in[11];
    const float* w_cas2 = (const float*)d_in[12]; const float* b_cas2 = (const float*)d_in[13];
    const float* w_om2  = (const float*)d_in[14]; const float* b_om2  = (const float*)d_in[15];
    const float* w_dcn2 = (const float*)d_in[16]; const float* b_dcn2 = (const float*)d_in[17];
    const float* w_ta1  = (const float*)d_in[18]; const float* b_ta1  = (const float*)d_in[19];
    const float* w_ta2  = (const float*)d_in[20]; const float* b_ta2  = (const float*)d_in[21];
    const float* w_ff   = (const float*)d_in[22]; const float* b_ff   = (const float*)d_in[23];

    constexpr int H = 180, W = 320, HW = H * W;
    constexpr size_t CHW = (size_t)HW * 64;
    constexpr size_t SLB = 4 * CHW * 2;                  // 29,491,200 B
    constexpr size_t OMSLOT_EL = (size_t)HW * 216;
    constexpr size_t OMSLOT_B  = OMSLOT_EL * 2;

    char* wsb = (char*)d_ws;
    unsigned short* S0 = (unsigned short*)(wsb);             // ref_t
    unsigned short* S1 = (unsigned short*)(wsb + SLB);       // neb_t -> cas_a -> feat3 ; ffw tail
    unsigned short* S2 = (unsigned short*)(wsb + 2 * SLB);   // off1 -> feat2 -> emb_ref
    unsigned short* S3 = (unsigned short*)(wsb + 3 * SLB);   // feat1 -> off2 -> corr
    float* corrf = (float*)S3;
    unsigned short* ffw = (unsigned short*)(wsb + SLB + (2u << 20));

    char* doutb = (char*)d_out;
    unsigned short* omA0 = (unsigned short*)doutb;
    unsigned short* omA1 = omA0 + OMSLOT_EL;
    unsigned short* wb   = (unsigned short*)(doutb + 2 * OMSLOT_B);
    const bool big = ws_size >= 4 * SLB + 2 * OMSLOT_B;
    unsigned short* omB0 = (unsigned short*)(wsb + 4 * SLB);
    unsigned short* omB1 = omB0 + OMSLOT_EL;

    unsigned short* w_oc1p = wb + 0;
    unsigned short* w_om1p = wb + 73728;
    unsigned short* w_dcn1p= wb + 221184;
    unsigned short* w_fcp  = wb + 258048;
    unsigned short* w_cas1p= wb + 294912;
    unsigned short* w_cas2p= wb + 368640;
    unsigned short* w_om2p = wb + 405504;
    unsigned short* w_dcn2p= wb + 552960;
    unsigned short* w_ta1p = wb + 589824;
    unsigned short* w_ta2p = wb + 626688;
    unsigned short* w_ffp  = wb + 663552;

    dim3 blk(256);
    dim3 g4(10, 45, 4);
    dim3 gm(10, 180, 2);

    nchw2nhwc<<<900, blk, 0, stream>>>(ref, S0);
    nchw2nhwc<<<900, blk, 0, stream>>>(neb, S1);
    auto PCW = [&](const float* src, unsigned short* dst, int cout, int cin, int nch){
        int total = nch * 9 * (cin / 32) * 2048;
        prep_conv_w<<<(total + 255) / 256, blk, 0, stream>>>(src, dst, cout, cin, total);
    };
    PCW(w_oc1, w_oc1p, 64, 128, 1);
    PCW(w_om1, w_om1p, 216, 64, 4);
    prep_dcn_w<<<144, blk, 0, stream>>>(w_dcn1, w_dcn1p);
    PCW(w_fc,  w_fcp,  64, 64, 1);
    PCW(w_cas1, w_cas1p, 64, 128, 1);
    PCW(w_cas2, w_cas2p, 64, 64, 1);
    PCW(w_om2, w_om2p, 216, 64, 4);
    prep_dcn_w<<<144, blk, 0, stream>>>(w_dcn2, w_dcn2p);
    PCW(w_ta1, w_ta1p, 64, 64, 1);
    PCW(w_ta2, w_ta2p, 64, 64, 1);
    PCW(w_ff,  w_ffp,  64, 64, 1);

    // 1. off1 = lrelu(conv(concat(neb,ref))) -> S2
    conv_mfma<128, true, true, false, 0><<<g4, blk, 0, stream>>>(
        S1, S0, w_oc1p, b_oc1, S2, nullptr, nullptr, nullptr, 64);

    auto omconv = [&](const unsigned short* inp, const unsigned short* wp, const float* bp,
                      unsigned short* slot){
        conv_mfma<64, false, false, false, 1><<<g4, blk, 0, stream>>>(
            inp, nullptr, wp, bp, slot, nullptr, nullptr, nullptr, 216);
    };

    // 2. pack1: om1 = conv(off1) [planar]; feat1 = mdcn(neb_t, om1) -> S3
    if (big) {
        omconv(S2 + 0 * CHW, w_om1p, b_om1, omA0);
        omconv(S2 + 1 * CHW, w_om1p, b_om1, omA1);
        omconv(S2 + 2 * CHW, w_om1p, b_om1, omB0);
        omconv(S2 + 3 * CHW, w_om1p, b_om1, omB1);
        mdcn_mfma<0><<<gm, blk, 0, stream>>>(S1, CHW, omA0, OMSLOT_EL, w_dcn1p, b_dcn1, S3, CHW);
        mdcn_mfma<0><<<gm, blk, 0, stream>>>(S1 + 2 * CHW, CHW, omB0, OMSLOT_EL, w_dcn1p, b_dcn1, S3 + 2 * CHW, CHW);
    } else {
        for (int pp = 0; pp < 2; ++pp) {
            omconv(S2 + (2 * pp) * CHW, w_om1p, b_om1, omA0);
            omconv(S2 + (2 * pp + 1) * CHW, w_om1p, b_om1, omA1);
            mdcn_mfma<0><<<gm, blk, 0, stream>>>(S1 + 2 * pp * CHW, CHW, omA0, OMSLOT_EL,
                                                 w_dcn1p, b_dcn1, S3 + 2 * pp * CHW, CHW);
        }
    }

    // 3. feat2 = lrelu(conv(feat1)) -> S2
    conv_mfma<64, false, true, false, 0><<<g4, blk, 0, stream>>>(
        S3, nullptr, w_fcp, b_fc, S2, nullptr, nullptr, nullptr, 64);
    // 4. cas_a = lrelu(conv(concat(feat2,ref))) -> S1
    conv_mfma<128, true, true, false, 0><<<g4, blk, 0, stream>>>(
        S2, S0, w_cas1p, b_cas1, S1, nullptr, nullptr, nullptr, 64);
    // 5. off2 = lrelu(conv(cas_a)) -> S3
    conv_mfma<64, false, true, false, 0><<<g4, blk, 0, stream>>>(
        S1, nullptr, w_cas2p, b_cas2, S3, nullptr, nullptr, nullptr, 64);

    // 6. pack2: om2 = conv(off2); feat3 = lrelu(mdcn(feat2, om2)) -> S1
    if (big) {
        omconv(S3 + 0 * CHW, w_om2p, b_om2, omA0);
        omconv(S3 + 1 * CHW, w_om2p, b_om2, omA1);
        omconv(S3 + 2 * CHW, w_om2p, b_om2, omB0);
        omconv(S3 + 3 * CHW, w_om2p, b_om2, omB1);
        mdcn_mfma<1><<<gm, blk, 0, stream>>>(S2, CHW, omA0, OMSLOT_EL, w_dcn2p, b_dcn2, S1, CHW);
        mdcn_mfma<1><<<gm, blk, 0, stream>>>(S2 + 2 * CHW, CHW, omB0, OMSLOT_EL, w_dcn2p, b_dcn2, S1 + 2 * CHW, CHW);
    } else {
        for (int pp = 0; pp < 2; ++pp) {
            omconv(S3 + (2 * pp) * CHW, w_om2p, b_om2, omA0);
            omconv(S3 + (2 * pp + 1) * CHW, w_om2p, b_om2, omA1);
            mdcn_mfma<1><<<gm, blk, 0, stream>>>(S2 + 2 * pp * CHW, CHW, omA0, OMSLOT_EL,
                                                 w_dcn2p, b_dcn2, S1 + 2 * pp * CHW, CHW);
        }
    }

    // 7. emb_ref = conv(ref_t, ta1) -> S2 ; corr = dot(conv(feat3, ta2), emb_ref) -> S3 (fused)
    conv_mfma<64, false, false, false, 0><<<g4, blk, 0, stream>>>(
        S0, nullptr, w_ta1p, b_ta1, S2, nullptr, nullptr, nullptr, 64);
    conv_mfma<64, false, false, false, 3><<<g4, blk, 0, stream>>>(
        S1, S2, w_ta2p, b_ta2, nullptr, nullptr, nullptr, corrf, 64);

    // relocate ff weights out of d_out before the final conv overwrites it
    hipMemcpyAsync(ffw, w_ffp, 36864 * 2, hipMemcpyDeviceToDevice, stream);

    // 8. out = lrelu(conv(ref_t*corr, ff)) + ref  (f32 NCHW into d_out)
    conv_mfma<64, false, true, true, 2><<<g4, blk, 0, stream>>>(
        S0, nullptr, ffw, b_ff, nullptr, corrf, ref, (float*)d_out, 64);
}

// Round 4
// 1294.696 us; speedup vs baseline: 6.7891x; 1.0647x over previous
//
#include <hip/hip_runtime.h>
#include <cmath>

// fusion_36455682409119 round 4:
//  - mdcn: single-phase 72-tap (36KB LDS, 4 blk/CU), FULLY UNROLLED taps,
//    planar om reads with all 27 loads hoisted to registers (pipelined gathers)
//  - weight prep: 13 launches -> 1 (PrepArgs table kernel)
//  - transposes: 2 launches -> 1
//  - convs + fused corr unchanged (round-3 proven)

using short8 = __attribute__((ext_vector_type(8))) short;
using f32x4  = __attribute__((ext_vector_type(4))) float;

#define DEVINL static __device__ __forceinline__

DEVINL unsigned short f2bf(float f){
    unsigned u = __float_as_uint(f);
    u += 0x7fffu + ((u >> 16) & 1u);
    return (unsigned short)(u >> 16);
}
DEVINL unsigned pack2(float a, float b){ return (unsigned)f2bf(a) | ((unsigned)f2bf(b) << 16); }
DEVINL float bflo(unsigned u){ return __uint_as_float(u << 16); }
DEVINL float bfhi(unsigned u){ return __uint_as_float(u & 0xffff0000u); }
DEVINL float bf2f(unsigned short u){ return __uint_as_float((unsigned)u << 16); }
DEVINL float lrelu_f(float v){ return v >= 0.f ? v : 0.1f * v; }

// ---------------- both NCHW f32 -> NHWC bf16 transposes in one launch ----------------
__global__ __launch_bounds__(256) void nchw2nhwc2(const float* __restrict__ inA,
                                                  const float* __restrict__ inB,
                                                  unsigned short* __restrict__ outA,
                                                  unsigned short* __restrict__ outB)
{
    constexpr int HW = 180 * 320;
    const int blk = blockIdx.x;
    const float* in = (blk < 900) ? inA : inB;
    unsigned short* out = (blk < 900) ? outA : outB;
    size_t idx = (size_t)(blk % 900) * 256 + threadIdx.x;
    size_t bb = idx / HW, p = idx % HW;
    const float* src = in + (bb * 64) * (size_t)HW + p;
    unsigned short* dst = out + idx * 64;
    #pragma unroll
    for (int c0 = 0; c0 < 64; c0 += 16) {
        unsigned r[8];
        #pragma unroll
        for (int q = 0; q < 8; ++q)
            r[q] = pack2(src[(size_t)(c0 + 2*q) * HW], src[(size_t)(c0 + 2*q + 1) * HW]);
        *(uint4*)(dst + c0)     = *(uint4*)&r[0];
        *(uint4*)(dst + c0 + 8) = *(uint4*)&r[4];
    }
}

// ---------------- all weight prepacks in one launch ----------------
// kind 0: conv order [ch][j][cs][64oc][32k], k=c.  kind 1: mdcn order [s(18)][64oc][32k].
struct PrepArgs {
    const float* src[11];
    unsigned short* dst[11];
    int cout[11]; int cin[11]; int nch[11]; int kind[11];
};

__global__ __launch_bounds__(256) void prep_all(PrepArgs a)
{
    const int t = blockIdx.y;
    const int idx = blockIdx.x * 256 + threadIdx.x;
    if (a.kind[t] == 1) {
        if (idx >= 36864) return;
        int kk = idx & 31, oc = (idx >> 5) & 63, s = idx >> 11;
        int k = s * 32 + kk;
        int gt = k >> 3, c8 = k & 7;
        int g = gt / 9, tp = gt - g * 9;
        a.dst[t][idx] = f2bf(a.src[t][((size_t)oc * 64 + g * 8 + c8) * 9 + tp]);
    } else {
        int cin = a.cin[t], cout = a.cout[t];
        int ncs = cin / 32;
        int total = a.nch[t] * 9 * ncs * 2048;
        if (idx >= total) return;
        int kk = idx & 31, oc_l = (idx >> 5) & 63, rest = idx >> 11;
        int cs = rest % ncs; int rest2 = rest / ncs;
        int j = rest2 % 9; int ch = rest2 / 9;
        int oc = ch * 64 + oc_l, c = cs * 32 + kk;
        float v = (oc < cout) ? a.src[t][((size_t)oc * cin + c) * 9 + j] : 0.f;
        a.dst[t][idx] = f2bf(v);
    }
}

// ---------------- MFMA conv 3x3 SAME, tile 64oc x (4row x 32col) ----------------
// OUTMODE 0: bf16 NHWC (stride 64). 1: bf16 PLANAR [COUT][HW], masked, b=0.
// 2: f32 NCHW out = lrelu(conv)+res. 3: corr fused — dot(conv_out, in1) -> outf f32.
template<int CIN, bool TWO_IN, bool ACT, bool SCALE, int OUTMODE>
__global__ __launch_bounds__(256, (CIN == 128 ? 2 : 3)) void conv_mfma(
    const unsigned short* __restrict__ in0, const unsigned short* __restrict__ in1,
    const unsigned short* __restrict__ wgt, const float* __restrict__ bias,
    unsigned short* __restrict__ out, const float* __restrict__ corr,
    const float* __restrict__ res, float* __restrict__ outf, int COUT)
{
    constexpr int H = 180, W = 320, HW = H * W;
    constexpr int NCB = CIN / 8;
    constexpr int NCS = CIN / 32;
    __shared__ __align__(16) unsigned char lds[6 * 34 * CIN * 2];

    const int tid = threadIdx.x;
    const int b  = (OUTMODE == 1) ? 0 : blockIdx.z;
    const int ch = (OUTMODE == 1) ? blockIdx.z : 0;
    const int x0 = blockIdx.x * 32, y0 = blockIdx.y * 4;

    for (int t = tid; t < 6 * 34 * NCB; t += 256) {
        int cb = t % NCB; int r = t / NCB;
        int xp = r % 34, yp = r / 34;
        int gx = x0 - 1 + xp, gy = y0 - 1 + yp;
        uint4 v = make_uint4(0, 0, 0, 0);
        if (gx >= 0 && gx < W && gy >= 0 && gy < H) {
            size_t pix = (size_t)b * HW + (size_t)gy * W + gx;
            const unsigned short* src;
            if (TWO_IN) src = (cb < 8) ? (in0 + pix * 64 + cb * 8) : (in1 + pix * 64 + (cb - 8) * 8);
            else        src = in0 + pix * CIN + cb * 8;
            v = *(const uint4*)src;
            if (SCALE) {
                float cv = corr[pix];
                v.x = pack2(bflo(v.x) * cv, bfhi(v.x) * cv);
                v.y = pack2(bflo(v.y) * cv, bfhi(v.y) * cv);
                v.z = pack2(bflo(v.z) * cv, bfhi(v.z) * cv);
                v.w = pack2(bflo(v.w) * cv, bfhi(v.w) * cv);
            }
        }
        int blk = cb ^ (xp & 7);
        *(uint4*)&lds[(size_t)((yp * 34 + xp) * NCB + blk) * 16] = v;
    }
    __syncthreads();

    const int wv = tid >> 6, lane = tid & 63;
    const int ll = lane & 15, lh = lane >> 4;
    const unsigned short* wchunk = wgt + (size_t)ch * (9 * NCS * 2048);
    const int alane = ll * 32 + lh * 8;

    f32x4 acc[4][2];
    #pragma unroll
    for (int mi = 0; mi < 4; ++mi)
        #pragma unroll
        for (int nf = 0; nf < 2; ++nf) acc[mi][nf] = f32x4{0.f, 0.f, 0.f, 0.f};

    #pragma unroll
    for (int j = 0; j < 9; ++j) {
        const int jy = j / 3, jx = j % 3;
        #pragma unroll
        for (int cs = 0; cs < NCS; ++cs) {
            const int s = j * NCS + cs;
            short8 a[4];
            #pragma unroll
            for (int mi = 0; mi < 4; ++mi)
                a[mi] = *(const short8*)(wchunk + (size_t)s * 2048 + mi * 512 + alane);
            short8 bf[2];
            #pragma unroll
            for (int nf = 0; nf < 2; ++nf) {
                int xp = nf * 16 + ll + jx;
                int blk = (cs * 4 + lh) ^ (xp & 7);
                int addr = (((wv + jy) * 34 + xp) * NCB + blk) * 16;
                bf[nf] = *(const short8*)&lds[addr];
            }
            #pragma unroll
            for (int mi = 0; mi < 4; ++mi)
                #pragma unroll
                for (int nf = 0; nf < 2; ++nf)
                    acc[mi][nf] = __builtin_amdgcn_mfma_f32_16x16x32_bf16(a[mi], bf[nf], acc[mi][nf], 0, 0, 0);
        }
    }

    const int py = y0 + wv;
    const size_t pixrow = (size_t)b * HW + (size_t)py * W;
    #pragma unroll
    for (int nf = 0; nf < 2; ++nf) {
        const int px = x0 + nf * 16 + ll;
        if (OUTMODE == 3) {
            float dot = 0.f;
            const unsigned* er = (const unsigned*)(in1 + (pixrow + px) * 64);
            #pragma unroll
            for (int mi = 0; mi < 4; ++mi) {
                const int oc_l = mi * 16 + lh * 4;
                unsigned e0 = er[oc_l / 2], e1 = er[oc_l / 2 + 1];
                float t0 = acc[mi][nf][0] + bias[oc_l + 0];
                float t1 = acc[mi][nf][1] + bias[oc_l + 1];
                float t2 = acc[mi][nf][2] + bias[oc_l + 2];
                float t3 = acc[mi][nf][3] + bias[oc_l + 3];
                dot += t0 * bflo(e0) + t1 * bfhi(e0) + t2 * bflo(e1) + t3 * bfhi(e1);
            }
            dot += __shfl_xor(dot, 16);
            dot += __shfl_xor(dot, 32);
            if (lh == 0) outf[pixrow + px] = dot;
        } else {
            #pragma unroll
            for (int mi = 0; mi < 4; ++mi) {
                const int oc_l = mi * 16 + lh * 4;
                if (OUTMODE == 0) {
                    float v[4];
                    #pragma unroll
                    for (int jj = 0; jj < 4; ++jj) {
                        float t = acc[mi][nf][jj] + bias[oc_l + jj];
                        v[jj] = ACT ? lrelu_f(t) : t;
                    }
                    uint2 st; st.x = pack2(v[0], v[1]); st.y = pack2(v[2], v[3]);
                    *(uint2*)&out[(pixrow + px) * 64 + oc_l] = st;
                } else if (OUTMODE == 1) {
                    #pragma unroll
                    for (int jj = 0; jj < 4; ++jj) {
                        int ocg = ch * 64 + oc_l + jj;
                        if (ocg < COUT) {
                            float t = acc[mi][nf][jj] + bias[ocg];
                            out[(size_t)ocg * HW + (size_t)py * W + px] = f2bf(ACT ? lrelu_f(t) : t);
                        }
                    }
                } else {
                    #pragma unroll
                    for (int jj = 0; jj < 4; ++jj) {
                        int oc = oc_l + jj;
                        float t = acc[mi][nf][jj] + bias[oc];
                        if (ACT) t = lrelu_f(t);
                        size_t idx = ((size_t)b * 64 + oc) * HW + (size_t)py * W + px;
                        outf[idx] = t + res[idx];
                    }
                }
            }
        }
    }
}

// ---------------- mdcn v2 (dg=8, Cg=8, 64->64) round-4 structure ----------------
// Single-phase 72 taps (36KB LDS). om PLANAR [216][HW]. Thread = (px, g); 9 taps
// fully unrolled; all 27 om loads hoisted so gathers pipeline.
template<int ACT>
__global__ __launch_bounds__(256, 4) void mdcn_mfma(
    const unsigned short* __restrict__ x, size_t xstride,
    const unsigned short* __restrict__ om, size_t omstride,
    const unsigned short* __restrict__ wgt, const float* __restrict__ bias,
    unsigned short* __restrict__ out, size_t ostride)
{
    constexpr int H = 180, W = 320, HW = H * W;
    __shared__ __align__(16) unsigned char sv[72 * 32 * 16];   // [tap_lin72][px32][8c]

    const int tid = threadIdx.x;
    const unsigned short* xb  = x  + (size_t)blockIdx.z * xstride;
    const unsigned short* omb = om + (size_t)blockIdx.z * omstride;
    unsigned short* ob        = out + (size_t)blockIdx.z * ostride;
    const int px0 = blockIdx.x * 32;
    const int py  = blockIdx.y;

    // phase 1: sampling
    {
        const int pxl = tid & 31, g = tid >> 5;
        const int px = px0 + pxl;
        const size_t p = (size_t)py * W + px;
        const unsigned short* omg = omb + (size_t)(g * 9) * HW + p;

        // hoist all om loads (independent, coalesced 64B lines per plane)
        float oyv[9], oxv[9], mmv[9];
        #pragma unroll
        for (int k = 0; k < 9; ++k) oyv[k] = bf2f(omg[(size_t)k * HW]);
        #pragma unroll
        for (int k = 0; k < 9; ++k) oxv[k] = bf2f(omg[(size_t)(72 + k) * HW]);
        #pragma unroll
        for (int k = 0; k < 9; ++k) mmv[k] = bf2f(omg[(size_t)(144 + k) * HW]);

        #pragma unroll
        for (int k = 0; k < 9; ++k) {
            float m = 1.f / (1.f + __expf(-mmv[k]));
            float pyf = (float)(py + (k / 3) - 1) + oyv[k];
            float pxf = (float)(px + (k % 3) - 1) + oxv[k];
            float y0f = floorf(pyf), x0f = floorf(pxf);
            float wy = pyf - y0f, wx = pxf - x0f;
            int yi = (int)y0f, xi = (int)x0f;
            bool vy0 = (yi >= 0) && (yi < H);
            bool vy1 = (yi + 1 >= 0) && (yi + 1 < H);
            bool vx0 = (xi >= 0) && (xi < W);
            bool vx1 = (xi + 1 >= 0) && (xi + 1 < W);
            float w00 = (vy0 && vx0) ? (1.f - wy) * (1.f - wx) * m : 0.f;
            float w01 = (vy0 && vx1) ? (1.f - wy) * wx * m : 0.f;
            float w10 = (vy1 && vx0) ? wy * (1.f - wx) * m : 0.f;
            float w11 = (vy1 && vx1) ? wy * wx * m : 0.f;
            int yc0 = min(max(yi, 0), H - 1), yc1 = min(max(yi + 1, 0), H - 1);
            int xc0 = min(max(xi, 0), W - 1), xc1 = min(max(xi + 1, 0), W - 1);
            uint4 c00 = *(const uint4*)(xb + ((size_t)(yc0 * W + xc0) * 64 + g * 8));
            uint4 c01 = *(const uint4*)(xb + ((size_t)(yc0 * W + xc1) * 64 + g * 8));
            uint4 c10 = *(const uint4*)(xb + ((size_t)(yc1 * W + xc0) * 64 + g * 8));
            uint4 c11 = *(const uint4*)(xb + ((size_t)(yc1 * W + xc1) * 64 + g * 8));
            const unsigned* p00 = (const unsigned*)&c00;
            const unsigned* p01 = (const unsigned*)&c01;
            const unsigned* p10 = (const unsigned*)&c10;
            const unsigned* p11 = (const unsigned*)&c11;
            unsigned r[4];
            #pragma unroll
            for (int q = 0; q < 4; ++q) {
                float lo = w00 * bflo(p00[q]) + w01 * bflo(p01[q]) + w10 * bflo(p10[q]) + w11 * bflo(p11[q]);
                float hi = w00 * bfhi(p00[q]) + w01 * bfhi(p01[q]) + w10 * bfhi(p10[q]) + w11 * bfhi(p11[q]);
                r[q] = pack2(lo, hi);
            }
            *(uint4*)&sv[(size_t)((g * 9 + k) * 32 + pxl) * 16] = *(uint4*)r;
        }
    }
    __syncthreads();

    // phase 2: MFMA, K=576 (18 steps)
    const int wv = tid >> 6, lane = tid & 63;
    const int ll = lane & 15, lh = lane >> 4;
    f32x4 acc[2] = {f32x4{0.f,0.f,0.f,0.f}, f32x4{0.f,0.f,0.f,0.f}};
    #pragma unroll
    for (int s = 0; s < 18; ++s) {
        short8 a = *(const short8*)(wgt + (size_t)(s * 64 + wv * 16 + ll) * 32 + lh * 8);
        #pragma unroll
        for (int nf = 0; nf < 2; ++nf) {
            short8 bb = *(const short8*)&sv[(size_t)s * 2048 + lh * 512 + (nf * 16 + ll) * 16];
            acc[nf] = __builtin_amdgcn_mfma_f32_16x16x32_bf16(a, bb, acc[nf], 0, 0, 0);
        }
    }
    #pragma unroll
    for (int nf = 0; nf < 2; ++nf) {
        int opx = px0 + nf * 16 + ll;
        int oc0 = wv * 16 + lh * 4;
        float v[4];
        #pragma unroll
        for (int jj = 0; jj < 4; ++jj) {
            float t = acc[nf][jj] + bias[oc0 + jj];
            v[jj] = ACT ? lrelu_f(t) : t;
        }
        uint2 st; st.x = pack2(v[0], v[1]); st.y = pack2(v[2], v[3]);
        *(uint2*)&ob[((size_t)py * W + opx) * 64 + oc0] = st;
    }
}

extern "C" void kernel_launch(void* const* d_in, const int* in_sizes, int n_in,
                              void* d_out, int out_size, void* d_ws, size_t ws_size,
                              hipStream_t stream)
{
    const float* ref    = (const float*)d_in[0];
    const float* neb    = (const float*)d_in[1];
    const float* w_oc1  = (const float*)d_in[2];  const float* b_oc1  = (const float*)d_in[3];
    const float* w_om1  = (const float*)d_in[4];  const float* b_om1  = (const float*)d_in[5];
    const float* w_dcn1 = (const float*)d_in[6];  const float* b_dcn1 = (const float*)d_in[7];
    const float* w_fc   = (const float*)d_in[8];  const float* b_fc   = (const float*)d_in[9];
    const float* w_cas1 = (const float*)d_in[10]; const float* b_cas1 = (const float*)d_in[11];
    const float* w_cas2 = (const float*)d_in[12]; const float* b_cas2 = (const float*)d_in[13];
    const float* w_om2  = (const float*)d_in[14]; const float* b_om2  = (const float*)d_in[15];
    const float* w_dcn2 = (const float*)d_in[16]; const float* b_dcn2 = (const float*)d_in[17];
    const float* w_ta1  = (const float*)d_in[18]; const float* b_ta1  = (const float*)d_in[19];
    const float* w_ta2  = (const float*)d_in[20]; const float* b_ta2  = (const float*)d_in[21];
    const float* w_ff   = (const float*)d_in[22]; const float* b_ff   = (const float*)d_in[23];

    constexpr int H = 180, W = 320, HW = H * W;
    constexpr size_t CHW = (size_t)HW * 64;
    constexpr size_t SLB = 4 * CHW * 2;
    constexpr size_t OMSLOT_EL = (size_t)HW * 216;
    constexpr size_t OMSLOT_B  = OMSLOT_EL * 2;

    char* wsb = (char*)d_ws;
    unsigned short* S0 = (unsigned short*)(wsb);
    unsigned short* S1 = (unsigned short*)(wsb + SLB);
    unsigned short* S2 = (unsigned short*)(wsb + 2 * SLB);
    unsigned short* S3 = (unsigned short*)(wsb + 3 * SLB);
    float* corrf = (float*)S3;
    unsigned short* ffw = (unsigned short*)(wsb + SLB + (2u << 20));

    char* doutb = (char*)d_out;
    unsigned short* omA0 = (unsigned short*)doutb;
    unsigned short* omA1 = omA0 + OMSLOT_EL;
    unsigned short* wb   = (unsigned short*)(doutb + 2 * OMSLOT_B);
    const bool big = ws_size >= 4 * SLB + 2 * OMSLOT_B;
    unsigned short* omB0 = (unsigned short*)(wsb + 4 * SLB);
    unsigned short* omB1 = omB0 + OMSLOT_EL;

    unsigned short* w_oc1p = wb + 0;
    unsigned short* w_om1p = wb + 73728;
    unsigned short* w_dcn1p= wb + 221184;
    unsigned short* w_fcp  = wb + 258048;
    unsigned short* w_cas1p= wb + 294912;
    unsigned short* w_cas2p= wb + 368640;
    unsigned short* w_om2p = wb + 405504;
    unsigned short* w_dcn2p= wb + 552960;
    unsigned short* w_ta1p = wb + 589824;
    unsigned short* w_ta2p = wb + 626688;
    unsigned short* w_ffp  = wb + 663552;

    dim3 blk(256);
    dim3 g4(10, 45, 4);
    dim3 gm(10, 180, 2);

    nchw2nhwc2<<<1800, blk, 0, stream>>>(ref, neb, S0, S1);

    {
        PrepArgs pa;
        const float* srcs[11] = {w_oc1, w_om1, w_dcn1, w_fc, w_cas1, w_cas2, w_om2, w_dcn2, w_ta1, w_ta2, w_ff};
        unsigned short* dsts[11] = {w_oc1p, w_om1p, w_dcn1p, w_fcp, w_cas1p, w_cas2p, w_om2p, w_dcn2p, w_ta1p, w_ta2p, w_ffp};
        int couts[11] = {64, 216, 0, 64, 64, 64, 216, 0, 64, 64, 64};
        int cins[11]  = {128, 64, 0, 64, 128, 64, 64, 0, 64, 64, 64};
        int nchs[11]  = {1, 4, 0, 1, 1, 1, 4, 0, 1, 1, 1};
        int kinds[11] = {0, 0, 1, 0, 0, 0, 0, 1, 0, 0, 0};
        for (int i = 0; i < 11; ++i) {
            pa.src[i] = srcs[i]; pa.dst[i] = dsts[i];
            pa.cout[i] = couts[i]; pa.cin[i] = cins[i]; pa.nch[i] = nchs[i]; pa.kind[i] = kinds[i];
        }
        prep_all<<<dim3(576, 11), blk, 0, stream>>>(pa);
    }

    // 1. off1 = lrelu(conv(concat(neb,ref))) -> S2
    conv_mfma<128, true, true, false, 0><<<g4, blk, 0, stream>>>(
        S1, S0, w_oc1p, b_oc1, S2, nullptr, nullptr, nullptr, 64);

    auto omconv = [&](const unsigned short* inp, const unsigned short* wp, const float* bp,
                      unsigned short* slot){
        conv_mfma<64, false, false, false, 1><<<g4, blk, 0, stream>>>(
            inp, nullptr, wp, bp, slot, nullptr, nullptr, nullptr, 216);
    };

    // 2. pack1: om1 = conv(off1) [planar]; feat1 = mdcn(neb_t, om1) -> S3
    if (big) {
        omconv(S2 + 0 * CHW, w_om1p, b_om1, omA0);
        omconv(S2 + 1 * CHW, w_om1p, b_om1, omA1);
        omconv(S2 + 2 * CHW, w_om1p, b_om1, omB0);
        omconv(S2 + 3 * CHW, w_om1p, b_om1, omB1);
        mdcn_mfma<0><<<gm, blk, 0, stream>>>(S1, CHW, omA0, OMSLOT_EL, w_dcn1p, b_dcn1, S3, CHW);
        mdcn_mfma<0><<<gm, blk, 0, stream>>>(S1 + 2 * CHW, CHW, omB0, OMSLOT_EL, w_dcn1p, b_dcn1, S3 + 2 * CHW, CHW);
    } else {
        for (int pp = 0; pp < 2; ++pp) {
            omconv(S2 + (2 * pp) * CHW, w_om1p, b_om1, omA0);
            omconv(S2 + (2 * pp + 1) * CHW, w_om1p, b_om1, omA1);
            mdcn_mfma<0><<<gm, blk, 0, stream>>>(S1 + 2 * pp * CHW, CHW, omA0, OMSLOT_EL,
                                                 w_dcn1p, b_dcn1, S3 + 2 * pp * CHW, CHW);
        }
    }

    // 3. feat2 = lrelu(conv(feat1)) -> S2
    conv_mfma<64, false, true, false, 0><<<g4, blk, 0, stream>>>(
        S3, nullptr, w_fcp, b_fc, S2, nullptr, nullptr, nullptr, 64);
    // 4. cas_a = lrelu(conv(concat(feat2,ref))) -> S1
    conv_mfma<128, true, true, false, 0><<<g4, blk, 0, stream>>>(
        S2, S0, w_cas1p, b_cas1, S1, nullptr, nullptr, nullptr, 64);
    // 5. off2 = lrelu(conv(cas_a)) -> S3
    conv_mfma<64, false, true, false, 0><<<g4, blk, 0, stream>>>(
        S1, nullptr, w_cas2p, b_cas2, S3, nullptr, nullptr, nullptr, 64);

    // 6. pack2: om2 = conv(off2); feat3 = lrelu(mdcn(feat2, om2)) -> S1
    if (big) {
        omconv(S3 + 0 * CHW, w_om2p, b_om2, omA0);
        omconv(S3 + 1 * CHW, w_om2p, b_om2, omA1);
        omconv(S3 + 2 * CHW, w_om2p, b_om2, omB0);
        omconv(S3 + 3 * CHW, w_om2p, b_om2, omB1);
        mdcn_mfma<1><<<gm, blk, 0, stream>>>(S2, CHW, omA0, OMSLOT_EL, w_dcn2p, b_dcn2, S1, CHW);
        mdcn_mfma<1><<<gm, blk, 0, stream>>>(S2 + 2 * CHW, CHW, omB0, OMSLOT_EL, w_dcn2p, b_dcn2, S1 + 2 * CHW, CHW);
    } else {
        for (int pp = 0; pp < 2; ++pp) {
            omconv(S3 + (2 * pp) * CHW, w_om2p, b_om2, omA0);
            omconv(S3 + (2 * pp + 1) * CHW, w_om2p, b_om2, omA1);
            mdcn_mfma<1><<<gm, blk, 0, stream>>>(S2 + 2 * pp * CHW, CHW, omA0, OMSLOT_EL,
                                                 w_dcn2p, b_dcn2, S1 + 2 * pp * CHW, CHW);
        }
    }

    // 7. emb_ref = conv(ref_t, ta1) -> S2 ; corr = dot(conv(feat3, ta2), emb_ref) -> S3 (fused)
    conv_mfma<64, false, false, false, 0><<<g4, blk, 0, stream>>>(
        S0, nullptr, w_ta1p, b_ta1, S2, nullptr, nullptr, nullptr, 64);
    conv_mfma<64, false, false, false, 3><<<g4, blk, 0, stream>>>(
        S1, S2, w_ta2p, b_ta2, nullptr, nullptr, nullptr, corrf, 64);

    // relocate ff weights out of d_out before the final conv overwrites it
    hipMemcpyAsync(ffw, w_ffp, 36864 * 2, hipMemcpyDeviceToDevice, stream);

    // 8. out = lrelu(conv(ref_t*corr, ff)) + ref  (f32 NCHW into d_out)
    conv_mfma<64, false, true, true, 2><<<g4, blk, 0, stream>>>(
        S0, nullptr, ffw, b_ff, nullptr, corrf, ref, (float*)d_out, 64);
}

// Round 5
// 1184.820 us; speedup vs baseline: 7.4187x; 1.0927x over previous
//
#include <hip/hip_runtime.h>
#include <cmath>

// fusion_36455682409119 round 5:
//  - XCD-aware bijective block swizzle (m204) on mdcn + all convs: each XCD gets
//    a contiguous y-band -> gather/halo working set fits the 4MiB per-XCD L2
//  - om convs: batched z=12 (chunks 0-2, NM=4) + z=4 tail (chunk 3, NM=2);
//    kills the 40/64 dead oc-rows of chunk 3 and 4 launches
//  - everything else: round-4 proven structure

using short8 = __attribute__((ext_vector_type(8))) short;
using f32x4  = __attribute__((ext_vector_type(4))) float;

#define DEVINL static __device__ __forceinline__

DEVINL unsigned short f2bf(float f){
    unsigned u = __float_as_uint(f);
    u += 0x7fffu + ((u >> 16) & 1u);
    return (unsigned short)(u >> 16);
}
DEVINL unsigned pack2(float a, float b){ return (unsigned)f2bf(a) | ((unsigned)f2bf(b) << 16); }
DEVINL float bflo(unsigned u){ return __uint_as_float(u << 16); }
DEVINL float bfhi(unsigned u){ return __uint_as_float(u & 0xffff0000u); }
DEVINL float bf2f(unsigned short u){ return __uint_as_float((unsigned)u << 16); }
DEVINL float lrelu_f(float v){ return v >= 0.f ? v : 0.1f * v; }

// m204 bijective XCD swizzle: physical blocks {p : p%8==i} execute a contiguous
// chunk of work ids -> XCD i's L2 sees a contiguous y-band.
DEVINL void swz_decode(int& bx, int& by, int& bz){
    const int gx = gridDim.x, gy = gridDim.y;
    int lin = blockIdx.x + gx * (blockIdx.y + gy * blockIdx.z);
    int nwg = gx * gy * gridDim.z;
    int q = nwg >> 3, r = nwg & 7;
    int xcd = lin & 7, idx = lin >> 3;
    int swz = (xcd < r ? xcd * (q + 1) : r + xcd * q) + idx;
    bz = swz / (gx * gy);
    int rem = swz - bz * gx * gy;
    by = rem / gx; bx = rem - by * gx;
}

struct Ptr4 { unsigned short* p[4]; };

// ---------------- both NCHW f32 -> NHWC bf16 transposes in one launch ----------------
__global__ __launch_bounds__(256) void nchw2nhwc2(const float* __restrict__ inA,
                                                  const float* __restrict__ inB,
                                                  unsigned short* __restrict__ outA,
                                                  unsigned short* __restrict__ outB)
{
    constexpr int HW = 180 * 320;
    const int blk = blockIdx.x;
    const float* in = (blk < 900) ? inA : inB;
    unsigned short* out = (blk < 900) ? outA : outB;
    size_t idx = (size_t)(blk % 900) * 256 + threadIdx.x;
    size_t bb = idx / HW, p = idx % HW;
    const float* src = in + (bb * 64) * (size_t)HW + p;
    unsigned short* dst = out + idx * 64;
    #pragma unroll
    for (int c0 = 0; c0 < 64; c0 += 16) {
        unsigned r[8];
        #pragma unroll
        for (int q = 0; q < 8; ++q)
            r[q] = pack2(src[(size_t)(c0 + 2*q) * HW], src[(size_t)(c0 + 2*q + 1) * HW]);
        *(uint4*)(dst + c0)     = *(uint4*)&r[0];
        *(uint4*)(dst + c0 + 8) = *(uint4*)&r[4];
    }
}

// ---------------- all weight prepacks in one launch ----------------
struct PrepArgs {
    const float* src[11];
    unsigned short* dst[11];
    int cout[11]; int cin[11]; int nch[11]; int kind[11];
};

__global__ __launch_bounds__(256) void prep_all(PrepArgs a)
{
    const int t = blockIdx.y;
    const int idx = blockIdx.x * 256 + threadIdx.x;
    if (a.kind[t] == 1) {
        if (idx >= 36864) return;
        int kk = idx & 31, oc = (idx >> 5) & 63, s = idx >> 11;
        int k = s * 32 + kk;
        int gt = k >> 3, c8 = k & 7;
        int g = gt / 9, tp = gt - g * 9;
        a.dst[t][idx] = f2bf(a.src[t][((size_t)oc * 64 + g * 8 + c8) * 9 + tp]);
    } else {
        int cin = a.cin[t], cout = a.cout[t];
        int ncs = cin / 32;
        int total = a.nch[t] * 9 * ncs * 2048;
        if (idx >= total) return;
        int kk = idx & 31, oc_l = (idx >> 5) & 63, rest = idx >> 11;
        int cs = rest % ncs; int rest2 = rest / ncs;
        int j = rest2 % 9; int ch = rest2 / 9;
        int oc = ch * 64 + oc_l, c = cs * 32 + kk;
        float v = (oc < cout) ? a.src[t][((size_t)oc * cin + c) * 9 + j] : 0.f;
        a.dst[t][idx] = f2bf(v);
    }
}

// ---------------- MFMA conv 3x3 SAME, tile (NM*16)oc x (4row x 32col) ----------------
// OUTMODE 0: bf16 NHWC (stride 64). 1: bf16 PLANAR [COUT][HW] via omout.p[b].
// 2: f32 NCHW out = lrelu(conv)+res. 3: corr fused -> outf f32.
template<int CIN, bool TWO_IN, bool ACT, bool SCALE, int OUTMODE, int NM>
__global__ __launch_bounds__(256, (CIN == 128 ? 2 : 3)) void conv_mfma(
    const unsigned short* __restrict__ in0, const unsigned short* __restrict__ in1,
    const unsigned short* __restrict__ wgt, const float* __restrict__ bias,
    unsigned short* __restrict__ out, const float* __restrict__ corr,
    const float* __restrict__ res, float* __restrict__ outf,
    Ptr4 omout, int choff, int zdiv, int COUT)
{
    constexpr int H = 180, W = 320, HW = H * W;
    constexpr int NCB = CIN / 8;
    constexpr int NCS = CIN / 32;
    __shared__ __align__(16) unsigned char lds[6 * 34 * CIN * 2];

    const int tid = threadIdx.x;
    int bx, by, bz;
    swz_decode(bx, by, bz);
    int b, ch;
    if (OUTMODE == 1) { b = bz / zdiv; ch = bz % zdiv + choff; }
    else              { b = bz; ch = 0; }
    const int x0 = bx * 32, y0 = by * 4;

    for (int t = tid; t < 6 * 34 * NCB; t += 256) {
        int cb = t % NCB; int r = t / NCB;
        int xp = r % 34, yp = r / 34;
        int gx = x0 - 1 + xp, gy = y0 - 1 + yp;
        uint4 v = make_uint4(0, 0, 0, 0);
        if (gx >= 0 && gx < W && gy >= 0 && gy < H) {
            size_t pix = (size_t)b * HW + (size_t)gy * W + gx;
            const unsigned short* src;
            if (TWO_IN) src = (cb < 8) ? (in0 + pix * 64 + cb * 8) : (in1 + pix * 64 + (cb - 8) * 8);
            else        src = in0 + pix * CIN + cb * 8;
            v = *(const uint4*)src;
            if (SCALE) {
                float cv = corr[pix];
                v.x = pack2(bflo(v.x) * cv, bfhi(v.x) * cv);
                v.y = pack2(bflo(v.y) * cv, bfhi(v.y) * cv);
                v.z = pack2(bflo(v.z) * cv, bfhi(v.z) * cv);
                v.w = pack2(bflo(v.w) * cv, bfhi(v.w) * cv);
            }
        }
        int blk = cb ^ (xp & 7);
        *(uint4*)&lds[(size_t)((yp * 34 + xp) * NCB + blk) * 16] = v;
    }
    __syncthreads();

    const int wv = tid >> 6, lane = tid & 63;
    const int ll = lane & 15, lh = lane >> 4;
    const unsigned short* wchunk = wgt + (size_t)ch * (9 * NCS * 2048);
    const int alane = ll * 32 + lh * 8;

    f32x4 acc[NM][2];
    #pragma unroll
    for (int mi = 0; mi < NM; ++mi)
        #pragma unroll
        for (int nf = 0; nf < 2; ++nf) acc[mi][nf] = f32x4{0.f, 0.f, 0.f, 0.f};

    #pragma unroll
    for (int j = 0; j < 9; ++j) {
        const int jy = j / 3, jx = j % 3;
        #pragma unroll
        for (int cs = 0; cs < NCS; ++cs) {
            const int s = j * NCS + cs;
            short8 a[NM];
            #pragma unroll
            for (int mi = 0; mi < NM; ++mi)
                a[mi] = *(const short8*)(wchunk + (size_t)s * 2048 + mi * 512 + alane);
            short8 bf[2];
            #pragma unroll
            for (int nf = 0; nf < 2; ++nf) {
                int xp = nf * 16 + ll + jx;
                int blk = (cs * 4 + lh) ^ (xp & 7);
                int addr = (((wv + jy) * 34 + xp) * NCB + blk) * 16;
                bf[nf] = *(const short8*)&lds[addr];
            }
            #pragma unroll
            for (int mi = 0; mi < NM; ++mi)
                #pragma unroll
                for (int nf = 0; nf < 2; ++nf)
                    acc[mi][nf] = __builtin_amdgcn_mfma_f32_16x16x32_bf16(a[mi], bf[nf], acc[mi][nf], 0, 0, 0);
        }
    }

    const int py = y0 + wv;
    const size_t pixrow = (size_t)b * HW + (size_t)py * W;
    #pragma unroll
    for (int nf = 0; nf < 2; ++nf) {
        const int px = x0 + nf * 16 + ll;
        if (OUTMODE == 3) {
            float dot = 0.f;
            const unsigned* er = (const unsigned*)(in1 + (pixrow + px) * 64);
            #pragma unroll
            for (int mi = 0; mi < NM; ++mi) {
                const int oc_l = mi * 16 + lh * 4;
                unsigned e0 = er[oc_l / 2], e1 = er[oc_l / 2 + 1];
                float t0 = acc[mi][nf][0] + bias[oc_l + 0];
                float t1 = acc[mi][nf][1] + bias[oc_l + 1];
                float t2 = acc[mi][nf][2] + bias[oc_l + 2];
                float t3 = acc[mi][nf][3] + bias[oc_l + 3];
                dot += t0 * bflo(e0) + t1 * bfhi(e0) + t2 * bflo(e1) + t3 * bfhi(e1);
            }
            dot += __shfl_xor(dot, 16);
            dot += __shfl_xor(dot, 32);
            if (lh == 0) outf[pixrow + px] = dot;
        } else if (OUTMODE == 1) {
            unsigned short* oslot = omout.p[b];
            #pragma unroll
            for (int mi = 0; mi < NM; ++mi) {
                const int oc_l = mi * 16 + lh * 4;
                #pragma unroll
                for (int jj = 0; jj < 4; ++jj) {
                    int ocg = ch * 64 + oc_l + jj;
                    if (ocg < COUT) {
                        float t = acc[mi][nf][jj] + bias[ocg];
                        oslot[(size_t)ocg * HW + (size_t)py * W + px] = f2bf(ACT ? lrelu_f(t) : t);
                    }
                }
            }
        } else {
            #pragma unroll
            for (int mi = 0; mi < NM; ++mi) {
                const int oc_l = mi * 16 + lh * 4;
                if (OUTMODE == 0) {
                    float v[4];
                    #pragma unroll
                    for (int jj = 0; jj < 4; ++jj) {
                        float t = acc[mi][nf][jj] + bias[oc_l + jj];
                        v[jj] = ACT ? lrelu_f(t) : t;
                    }
                    uint2 st; st.x = pack2(v[0], v[1]); st.y = pack2(v[2], v[3]);
                    *(uint2*)&out[(pixrow + px) * 64 + oc_l] = st;
                } else {
                    #pragma unroll
                    for (int jj = 0; jj < 4; ++jj) {
                        int oc = oc_l + jj;
                        float t = acc[mi][nf][jj] + bias[oc];
                        if (ACT) t = lrelu_f(t);
                        size_t idx = ((size_t)b * 64 + oc) * HW + (size_t)py * W + px;
                        outf[idx] = t + res[idx];
                    }
                }
            }
        }
    }
}

// ---------------- mdcn v2 (dg=8, Cg=8, 64->64), XCD-swizzled ----------------
template<int ACT>
__global__ __launch_bounds__(256, 4) void mdcn_mfma(
    const unsigned short* __restrict__ x, size_t xstride,
    const unsigned short* __restrict__ om, size_t omstride,
    const unsigned short* __restrict__ wgt, const float* __restrict__ bias,
    unsigned short* __restrict__ out, size_t ostride)
{
    constexpr int H = 180, W = 320, HW = H * W;
    __shared__ __align__(16) unsigned char sv[72 * 32 * 16];

    const int tid = threadIdx.x;
    int bx, by, bz;
    swz_decode(bx, by, bz);
    const unsigned short* xb  = x  + (size_t)bz * xstride;
    const unsigned short* omb = om + (size_t)bz * omstride;
    unsigned short* ob        = out + (size_t)bz * ostride;
    const int px0 = bx * 32;
    const int py  = by;

    // phase 1: sampling
    {
        const int pxl = tid & 31, g = tid >> 5;
        const int px = px0 + pxl;
        const size_t p = (size_t)py * W + px;
        const unsigned short* omg = omb + (size_t)(g * 9) * HW + p;

        float oyv[9], oxv[9], mmv[9];
        #pragma unroll
        for (int k = 0; k < 9; ++k) oyv[k] = bf2f(omg[(size_t)k * HW]);
        #pragma unroll
        for (int k = 0; k < 9; ++k) oxv[k] = bf2f(omg[(size_t)(72 + k) * HW]);
        #pragma unroll
        for (int k = 0; k < 9; ++k) mmv[k] = bf2f(omg[(size_t)(144 + k) * HW]);

        #pragma unroll
        for (int k = 0; k < 9; ++k) {
            float m = 1.f / (1.f + __expf(-mmv[k]));
            float pyf = (float)(py + (k / 3) - 1) + oyv[k];
            float pxf = (float)(px + (k % 3) - 1) + oxv[k];
            float y0f = floorf(pyf), x0f = floorf(pxf);
            float wy = pyf - y0f, wx = pxf - x0f;
            int yi = (int)y0f, xi = (int)x0f;
            bool vy0 = (yi >= 0) && (yi < H);
            bool vy1 = (yi + 1 >= 0) && (yi + 1 < H);
            bool vx0 = (xi >= 0) && (xi < W);
            bool vx1 = (xi + 1 >= 0) && (xi + 1 < W);
            float w00 = (vy0 && vx0) ? (1.f - wy) * (1.f - wx) * m : 0.f;
            float w01 = (vy0 && vx1) ? (1.f - wy) * wx * m : 0.f;
            float w10 = (vy1 && vx0) ? wy * (1.f - wx) * m : 0.f;
            float w11 = (vy1 && vx1) ? wy * wx * m : 0.f;
            int yc0 = min(max(yi, 0), H - 1), yc1 = min(max(yi + 1, 0), H - 1);
            int xc0 = min(max(xi, 0), W - 1), xc1 = min(max(xi + 1, 0), W - 1);
            uint4 c00 = *(const uint4*)(xb + ((size_t)(yc0 * W + xc0) * 64 + g * 8));
            uint4 c01 = *(const uint4*)(xb + ((size_t)(yc0 * W + xc1) * 64 + g * 8));
            uint4 c10 = *(const uint4*)(xb + ((size_t)(yc1 * W + xc0) * 64 + g * 8));
            uint4 c11 = *(const uint4*)(xb + ((size_t)(yc1 * W + xc1) * 64 + g * 8));
            const unsigned* p00 = (const unsigned*)&c00;
            const unsigned* p01 = (const unsigned*)&c01;
            const unsigned* p10 = (const unsigned*)&c10;
            const unsigned* p11 = (const unsigned*)&c11;
            unsigned r[4];
            #pragma unroll
            for (int q = 0; q < 4; ++q) {
                float lo = w00 * bflo(p00[q]) + w01 * bflo(p01[q]) + w10 * bflo(p10[q]) + w11 * bflo(p11[q]);
                float hi = w00 * bfhi(p00[q]) + w01 * bfhi(p01[q]) + w10 * bfhi(p10[q]) + w11 * bfhi(p11[q]);
                r[q] = pack2(lo, hi);
            }
            *(uint4*)&sv[(size_t)((g * 9 + k) * 32 + pxl) * 16] = *(uint4*)r;
        }
    }
    __syncthreads();

    // phase 2: MFMA, K=576 (18 steps)
    const int wv = tid >> 6, lane = tid & 63;
    const int ll = lane & 15, lh = lane >> 4;
    f32x4 acc[2] = {f32x4{0.f,0.f,0.f,0.f}, f32x4{0.f,0.f,0.f,0.f}};
    #pragma unroll
    for (int s = 0; s < 18; ++s) {
        short8 a = *(const short8*)(wgt + (size_t)(s * 64 + wv * 16 + ll) * 32 + lh * 8);
        #pragma unroll
        for (int nf = 0; nf < 2; ++nf) {
            short8 bb = *(const short8*)&sv[(size_t)s * 2048 + lh * 512 + (nf * 16 + ll) * 16];
            acc[nf] = __builtin_amdgcn_mfma_f32_16x16x32_bf16(a, bb, acc[nf], 0, 0, 0);
        }
    }
    #pragma unroll
    for (int nf = 0; nf < 2; ++nf) {
        int opx = px0 + nf * 16 + ll;
        int oc0 = wv * 16 + lh * 4;
        float v[4];
        #pragma unroll
        for (int jj = 0; jj < 4; ++jj) {
            float t = acc[nf][jj] + bias[oc0 + jj];
            v[jj] = ACT ? lrelu_f(t) : t;
        }
        uint2 st; st.x = pack2(v[0], v[1]); st.y = pack2(v[2], v[3]);
        *(uint2*)&ob[((size_t)py * W + opx) * 64 + oc0] = st;
    }
}

extern "C" void kernel_launch(void* const* d_in, const int* in_sizes, int n_in,
                              void* d_out, int out_size, void* d_ws, size_t ws_size,
                              hipStream_t stream)
{
    const float* ref    = (const float*)d_in[0];
    const float* neb    = (const float*)d_in[1];
    const float* w_oc1  = (const float*)d_in[2];  const float* b_oc1  = (const float*)d_in[3];
    const float* w_om1  = (const float*)d_in[4];  const float* b_om1  = (const float*)d_in[5];
    const float* w_dcn1 = (const float*)d_in[6];  const float* b_dcn1 = (const float*)d_in[7];
    const float* w_fc   = (const float*)d_in[8];  const float* b_fc   = (const float*)d_in[9];
    const float* w_cas1 = (const float*)d_in[10]; const float* b_cas1 = (const float*)d_in[11];
    const float* w_cas2 = (const float*)d_in[12]; const float* b_cas2 = (const float*)d_in[13];
    const float* w_om2  = (const float*)d_in[14]; const float* b_om2  = (const float*)d_in[15];
    const float* w_dcn2 = (const float*)d_in[16]; const float* b_dcn2 = (const float*)d_in[17];
    const float* w_ta1  = (const float*)d_in[18]; const float* b_ta1  = (const float*)d_in[19];
    const float* w_ta2  = (const float*)d_in[20]; const float* b_ta2  = (const float*)d_in[21];
    const float* w_ff   = (const float*)d_in[22]; const float* b_ff   = (const float*)d_in[23];

    constexpr int H = 180, W = 320, HW = H * W;
    constexpr size_t CHW = (size_t)HW * 64;
    constexpr size_t SLB = 4 * CHW * 2;
    constexpr size_t OMSLOT_EL = (size_t)HW * 216;
    constexpr size_t OMSLOT_B  = OMSLOT_EL * 2;

    char* wsb = (char*)d_ws;
    unsigned short* S0 = (unsigned short*)(wsb);
    unsigned short* S1 = (unsigned short*)(wsb + SLB);
    unsigned short* S2 = (unsigned short*)(wsb + 2 * SLB);
    unsigned short* S3 = (unsigned short*)(wsb + 3 * SLB);
    float* corrf = (float*)S3;
    unsigned short* ffw = (unsigned short*)(wsb + SLB + (2u << 20));

    char* doutb = (char*)d_out;
    unsigned short* omA0 = (unsigned short*)doutb;
    unsigned short* omA1 = omA0 + OMSLOT_EL;
    unsigned short* wb   = (unsigned short*)(doutb + 2 * OMSLOT_B);
    const bool big = ws_size >= 4 * SLB + 2 * OMSLOT_B;
    unsigned short* omB0 = (unsigned short*)(wsb + 4 * SLB);
    unsigned short* omB1 = omB0 + OMSLOT_EL;

    unsigned short* w_oc1p = wb + 0;
    unsigned short* w_om1p = wb + 73728;
    unsigned short* w_dcn1p= wb + 221184;
    unsigned short* w_fcp  = wb + 258048;
    unsigned short* w_cas1p= wb + 294912;
    unsigned short* w_cas2p= wb + 368640;
    unsigned short* w_om2p = wb + 405504;
    unsigned short* w_dcn2p= wb + 552960;
    unsigned short* w_ta1p = wb + 589824;
    unsigned short* w_ta2p = wb + 626688;
    unsigned short* w_ffp  = wb + 663552;

    dim3 blk(256);
    dim3 g4(10, 45, 4);
    dim3 gm(10, 180, 2);
    Ptr4 none{};

    nchw2nhwc2<<<1800, blk, 0, stream>>>(ref, neb, S0, S1);

    {
        PrepArgs pa;
        const float* srcs[11] = {w_oc1, w_om1, w_dcn1, w_fc, w_cas1, w_cas2, w_om2, w_dcn2, w_ta1, w_ta2, w_ff};
        unsigned short* dsts[11] = {w_oc1p, w_om1p, w_dcn1p, w_fcp, w_cas1p, w_cas2p, w_om2p, w_dcn2p, w_ta1p, w_ta2p, w_ffp};
        int couts[11] = {64, 216, 0, 64, 64, 64, 216, 0, 64, 64, 64};
        int cins[11]  = {128, 64, 0, 64, 128, 64, 64, 0, 64, 64, 64};
        int nchs[11]  = {1, 4, 0, 1, 1, 1, 4, 0, 1, 1, 1};
        int kinds[11] = {0, 0, 1, 0, 0, 0, 0, 1, 0, 0, 0};
        for (int i = 0; i < 11; ++i) {
            pa.src[i] = srcs[i]; pa.dst[i] = dsts[i];
            pa.cout[i] = couts[i]; pa.cin[i] = cins[i]; pa.nch[i] = nchs[i]; pa.kind[i] = kinds[i];
        }
        prep_all<<<dim3(576, 11), blk, 0, stream>>>(pa);
    }

    // 1. off1 = lrelu(conv(concat(neb,ref))) -> S2
    conv_mfma<128, true, true, false, 0, 4><<<g4, blk, 0, stream>>>(
        S1, S0, w_oc1p, b_oc1, S2, nullptr, nullptr, nullptr, none, 0, 1, 64);

    // om conv: chunks 0-2 full (NM=4, z = 4b*? -> b*zdiv+ch), chunk 3 tail (NM=2)
    auto ompack = [&](const unsigned short* inp, const unsigned short* wp, const float* bp,
                      Ptr4 slots, int nb){
        conv_mfma<64, false, false, false, 1, 4><<<dim3(10, 45, 3 * nb), blk, 0, stream>>>(
            inp, nullptr, wp, bp, nullptr, nullptr, nullptr, nullptr, slots, 0, 3, 216);
        conv_mfma<64, false, false, false, 1, 2><<<dim3(10, 45, nb), blk, 0, stream>>>(
            inp, nullptr, wp, bp, nullptr, nullptr, nullptr, nullptr, slots, 3, 1, 216);
    };

    // 2. pack1: om1 = conv(off1) [planar]; feat1 = mdcn(neb_t, om1) -> S3
    if (big) {
        Ptr4 slots{omA0, omA1, omB0, omB1};
        ompack(S2, w_om1p, b_om1, slots, 4);
        mdcn_mfma<0><<<gm, blk, 0, stream>>>(S1, CHW, omA0, OMSLOT_EL, w_dcn1p, b_dcn1, S3, CHW);
        mdcn_mfma<0><<<gm, blk, 0, stream>>>(S1 + 2 * CHW, CHW, omB0, OMSLOT_EL, w_dcn1p, b_dcn1, S3 + 2 * CHW, CHW);
    } else {
        Ptr4 slots{omA0, omA1, nullptr, nullptr};
        for (int pp = 0; pp < 2; ++pp) {
            ompack(S2 + 2 * pp * CHW, w_om1p, b_om1, slots, 2);
            mdcn_mfma<0><<<gm, blk, 0, stream>>>(S1 + 2 * pp * CHW, CHW, omA0, OMSLOT_EL,
                                                 w_dcn1p, b_dcn1, S3 + 2 * pp * CHW, CHW);
        }
    }

    // 3. feat2 = lrelu(conv(feat1)) -> S2
    conv_mfma<64, false, true, false, 0, 4><<<g4, blk, 0, stream>>>(
        S3, nullptr, w_fcp, b_fc, S2, nullptr, nullptr, nullptr, none, 0, 1, 64);
    // 4. cas_a = lrelu(conv(concat(feat2,ref))) -> S1
    conv_mfma<128, true, true, false, 0, 4><<<g4, blk, 0, stream>>>(
        S2, S0, w_cas1p, b_cas1, S1, nullptr, nullptr, nullptr, none, 0, 1, 64);
    // 5. off2 = lrelu(conv(cas_a)) -> S3
    conv_mfma<64, false, true, false, 0, 4><<<g4, blk, 0, stream>>>(
        S1, nullptr, w_cas2p, b_cas2, S3, nullptr, nullptr, nullptr, none, 0, 1, 64);

    // 6. pack2: om2 = conv(off2); feat3 = lrelu(mdcn(feat2, om2)) -> S1
    if (big) {
        Ptr4 slots{omA0, omA1, omB0, omB1};
        ompack(S3, w_om2p, b_om2, slots, 4);
        mdcn_mfma<1><<<gm, blk, 0, stream>>>(S2, CHW, omA0, OMSLOT_EL, w_dcn2p, b_dcn2, S1, CHW);
        mdcn_mfma<1><<<gm, blk, 0, stream>>>(S2 + 2 * CHW, CHW, omB0, OMSLOT_EL, w_dcn2p, b_dcn2, S1 + 2 * CHW, CHW);
    } else {
        Ptr4 slots{omA0, omA1, nullptr, nullptr};
        for (int pp = 0; pp < 2; ++pp) {
            ompack(S3 + 2 * pp * CHW, w_om2p, b_om2, slots, 2);
            mdcn_mfma<1><<<gm, blk, 0, stream>>>(S2 + 2 * pp * CHW, CHW, omA0, OMSLOT_EL,
                                                 w_dcn2p, b_dcn2, S1 + 2 * pp * CHW, CHW);
        }
    }

    // 7. emb_ref = conv(ref_t, ta1) -> S2 ; corr = dot(conv(feat3, ta2), emb_ref) (fused)
    conv_mfma<64, false, false, false, 0, 4><<<g4, blk, 0, stream>>>(
        S0, nullptr, w_ta1p, b_ta1, S2, nullptr, nullptr, nullptr, none, 0, 1, 64);
    conv_mfma<64, false, false, false, 3, 4><<<g4, blk, 0, stream>>>(
        S1, S2, w_ta2p, b_ta2, nullptr, nullptr, nullptr, corrf, none, 0, 1, 64);

    // relocate ff weights out of d_out before the final conv overwrites it
    hipMemcpyAsync(ffw, w_ffp, 36864 * 2, hipMemcpyDeviceToDevice, stream);

    // 8. out = lrelu(conv(ref_t*corr, ff)) + ref  (f32 NCHW into d_out)
    conv_mfma<64, false, true, true, 2, 4><<<g4, blk, 0, stream>>>(
        S0, nullptr, ffw, b_ff, nullptr, corrf, ref, (float*)d_out, none, 0, 1, 64);
}